// Round 13
// baseline (303.427 us; speedup 1.0000x reference)
//
#include <hip/hip_runtime.h>
#include <math.h>

// Shapes (fixed by the reference)
#define DXc   16
#define MRc   64
#define MBARc 256
#define NTc   9
#define DYc   8
#define HXc   1024
#define EXc   512
#define HRc   512
#define HBc   2048
#define GOUTc 64
#define TOTc  2049   // (NT-1)*MBAR + 1

using bf16x8 = __attribute__((ext_vector_type(8))) short;
using f32x4  = __attribute__((ext_vector_type(4))) float;

typedef unsigned int u32;
typedef u32 __attribute__((address_space(1))) gbl_u32;
typedef u32 __attribute__((address_space(3))) lds_u32;

__device__ __forceinline__ float fast_tanh(float x){
    float e = __expf(2.0f * x);
    return 1.0f - 2.0f / (e + 1.0f);
}

// fp32 -> bf16 round-to-nearest-even (bit pattern in a short)
__device__ __forceinline__ short f2bf(float f){
    unsigned u = __builtin_bit_cast(unsigned, f);
    u = (u + 0x7FFFu + ((u >> 16) & 1u)) >> 16;
    return (short)u;
}

// async global->LDS: each lane loads 16 B from g + lane*16; LDS dest = base + lane*16
__device__ __forceinline__ void gld_lds16(const short* g, short* l){
    __builtin_amdgcn_global_load_lds((const gbl_u32*)g, (lds_u32*)l, 16, 0, 0);
}

// ---------------- prep: SW + packs + XW/T1 + wrow + c0row(64-block parallel) + inits ----------------
// grid 2177 x 256
__global__ void prep_kernel(const float* __restrict__ stoich, const float* __restrict__ Wx1,
                            const float* __restrict__ Wx2, const float* __restrict__ Wb1,
                            const float* __restrict__ X, const float* __restrict__ R,
                            const float* __restrict__ bx1, const float* __restrict__ bx2,
                            const float* __restrict__ bb1,
                            const int* kpptr, const int* qpptr,
                            float* __restrict__ SW, short* __restrict__ Wx2a,
                            short* __restrict__ Wb1p, float* __restrict__ XW,
                            float* __restrict__ T1, float* __restrict__ wrow,
                            float* __restrict__ hb0, float* __restrict__ dacc,
                            float* __restrict__ outz, float* __restrict__ c0row,
                            float* __restrict__ cY, int* __restrict__ cnt){
    int b = blockIdx.x, tid = threadIdx.x;
    if (b < 256){
        // SW[j][c] = stoich[:,j] @ Wx1
        int idx = b * 256 + tid;
        int j = idx >> 10, c = idx & 1023;
        float acc = 0.f;
        #pragma unroll
        for (int d = 0; d < DXc; ++d) acc += stoich[d * MRc + j] * Wx1[d * HXc + c];
        SW[idx] = acc;
    } else if (b < 512){
        // pack Wx2 (1024x512) into MFMA A-fragment order (M=c rows, K=e), KTOT=16, layout [chunk][kt][512]
        size_t grp = (size_t)(b - 256) * 256 + tid;    // 65536 groups
        int lane = grp & 63;
        size_t t2 = grp >> 6;
        int kt = t2 & 15, mt = t2 >> 4;                // mt 0..63
        int c  = mt * 16 + (lane & 15);
        int e0 = kt * 32 + ((lane >> 4) << 3);
        short o8[8];
        #pragma unroll
        for (int jj = 0; jj < 8; ++jj) o8[jj] = f2bf(Wx2[(size_t)c * EXc + e0 + jj]);
        *(bf16x8*)(Wx2a + grp * 8) = *(bf16x8*)o8;
    } else if (b < 1024){
        // pack Wb1 rows 1..512 (512x2048) into B-fragment order, KTOT=16, layout [chunk][kt][512]
        size_t grp = (size_t)(b - 512) * 256 + tid;
        int lane = grp & 63;
        size_t t2 = grp >> 6;
        int kt = t2 & 15, nt = t2 >> 4;
        int n  = nt * 16 + (lane & 15);
        int k0 = kt * 32 + ((lane >> 4) << 3);
        short o8[8];
        #pragma unroll
        for (int jj = 0; jj < 8; ++jj) o8[jj] = f2bf(Wb1[(size_t)(1 + k0 + jj) * HBc + n]);
        *(bf16x8*)(Wb1p + grp * 8) = *(bf16x8*)o8;
    } else if (b < 2048){
        // XW = Xbase@Wx1 + bx1 ; T1 = tanh(XW)
        int idx = (b - 1024) * 256 + tid;
        int m = idx >> 10, c = idx & 1023;
        int base = kpptr[0] * MBARc;
        const float* xr = X + ((size_t)qpptr[0] * TOTc + base + m) * DXc;
        float acc = bx1[c];
        #pragma unroll
        for (int d = 0; d < DXc; ++d) acc += xr[d] * Wx1[d * HXc + c];
        XW[idx] = acc;
        T1[idx] = fast_tanh(acc);
    } else if (b < 2112){
        // wrow[j*256+m] = valid(j,m) * R_delta
        int j = b - 2048, m = tid;
        int base = kpptr[0] * MBARc;
        int qp = qpptr[0];
        const float* xr = X + ((size_t)qp * TOTc + base + m) * DXc;
        bool valid = true;
        #pragma unroll
        for (int d = 0; d < DXc; ++d) valid = valid && (xr[d] + stoich[d * MRc + j] >= 0.f);
        size_t rb = (size_t)qp * TOTc * MRc;
        float rd = R[rb + (size_t)(base + 1 + m) * MRc + j] - R[rb + (size_t)(base + m) * MRc + j];
        wrow[j * MBARc + m] = valid ? rd : 0.f;
    } else if (b == 2112){
        hb0[tid] = 0.f; hb0[tid + 256] = 0.f;
        #pragma unroll
        for (int l = 0; l < 8; ++l) dacc[tid + l * 256] = 0.f;
        #pragma unroll
        for (int l = 0; l < 8; ++l) cY[tid + l * 256] = bb1[tid + l * 256];
        if (tid < GOUTc) outz[tid] = 0.f;
        if (tid == 0){ cnt[0] = 0; cnt[1] = 0; cnt[2] = 0; cnt[3] = 0; }
    } else {
        // c0row[h] = bx2 @ Wb1[1:513, h]; 64 blocks x 32 h, 8 e-segments reduced in LDS
        __shared__ float cps[32][8];
        int bb = b - 2113;                  // 0..63
        int hl = tid & 31, sg = tid >> 5;   // 32 h x 8 segs
        int h = bb * 32 + hl, e0 = sg * 64;
        float a = 0.f;
        #pragma unroll 8
        for (int e = 0; e < 64; ++e)
            a += bx2[e0 + e] * Wb1[(size_t)(1 + e0 + e) * HBc + h];
        cps[hl][sg] = a;
        __syncthreads();
        if (sg == 0){
            float s = 0.f;
            #pragma unroll
            for (int r = 0; r < 8; ++r) s += cps[hl][r];
            c0row[h] = s;
        }
    }
}

// ---- MFMA helpers (4x4 grid, used by w12) ----
#define MMGRID(aa, bb) {                                                       \
    _Pragma("unroll") for (int i_ = 0; i_ < 4; ++i_)                           \
        _Pragma("unroll") for (int j_ = 0; j_ < 4; ++j_)                       \
            acc[i_][j_] = __builtin_amdgcn_mfma_f32_16x16x32_bf16(aa[i_], bb[j_], acc[i_][j_], 0, 0, 0); }

// stage BK=32 (1 kt) from [chunk][kt][512] layout: 8 A + 8 B chunks of 1 KB; waves 0..3 stage 4 each
__device__ __forceinline__ void stage32(const short* __restrict__ Ap, const short* __restrict__ Bp,
                                        short* As, short* Bs,
                                        int at0, int bt0, int s, int KTOT, int wave, int lane){
    #pragma unroll
    for (int c = 0; c < 4; ++c){
        int ci = wave * 4 + c;            // 0..15
        int half = ci >> 3;               // 0 = A, 1 = B
        int t    = ci & 7;
        const short* src = half ? (Bp + ((size_t)(bt0 + t) * KTOT + s) * 512 + lane * 8)
                                : (Ap + ((size_t)(at0 + t) * KTOT + s) * 512 + lane * 8);
        short* dst = (half ? Bs : As) + t * 512;
        gld_lds16(src, dst);
    }
}

#define STAGE_COMPUTE(As, Bs) {                                                       \
    bf16x8 af[4], bfr[4];                                                             \
    _Pragma("unroll") for (int i_ = 0; i_ < 4; ++i_)                                  \
        af[i_] = *(const bf16x8*)((As) + ((wm * 4 + i_) * 512) + lane * 8);           \
    _Pragma("unroll") for (int j_ = 0; j_ < 4; ++j_)                                  \
        bfr[j_] = *(const bf16x8*)((Bs) + ((wn * 4 + j_) * 512) + lane * 8);          \
    MMGRID(af, bfr); }

// ================ mid: RNN + cY + w12 + T1p + tbgemm + act_delta, ONE dispatch ================
// blocks [0,8):      RNN, Whh slice in 64 VGPR/thread; cnt[0] step protocol
// blocks [8,24):     cY (sleep-spin cnt[0]==64), signals cnt[3]
// blocks [24,152):   w12 gemm (dbuf 32KB, waves 0..3), signals cnt[1]
// blocks [152,216):  T1p pack, signals cnt[2]
// blocks [216,280):  tbgemm: spin cnt[1]==128 && cnt[2]==64 -> K-loop (overlaps RNN tail)
//                    -> spin cnt[3]==16 -> epilogue writes TB.  (split-phase: K-loop off the
//                    serial RNN chain; producers all at lower block IDs -> no deadlock)
// blocks [280,4376): act_delta
// Producer->consumer handshake = normal stores + __threadfence + release counter; consumer
// acquire-spin then plain loads (pattern proven correct in R10's TB handoff).
__global__ __launch_bounds__(512) void mid_kernel(
    const float* __restrict__ XW, const float* __restrict__ T1,
    const float* __restrict__ SW, short* __restrict__ A1p, short* __restrict__ T1p,
    const float* __restrict__ Y, const float* __restrict__ Wih,
    const float* __restrict__ Whh, const float* __restrict__ bh,
    const float* __restrict__ Wb1,
    const int* kptr, const int* qptr,
    float* __restrict__ hb0, float* __restrict__ hb1,
    int* __restrict__ cnt, float* __restrict__ cY,
    const short* __restrict__ Wx2a, const short* __restrict__ Wb1p,
    short* __restrict__ W12p,
    const float* __restrict__ c0row, const float* __restrict__ times_t,
    const float* __restrict__ times_tau, float* __restrict__ TB){
    __shared__ __align__(16) char smem[32768];   // union: rnn 4K | cY 0.5K | w12 32K | tb 24K
    int b = blockIdx.x, tid = threadIdx.x;
    if (b < 8){
        // ---- RNN: Whh[:, out] segment in registers; 8 blocks co-resident, cnt-gated ----
        float* hs = (float*)smem;                              // 512
        float (*psum)[64] = (float(*)[64])(smem + 2048);       // [8][64]
        int o = tid & 63, seg = tid >> 6;
        int out = b * 64 + o;
        int k = kptr[0], q = qptr[0];
        float wreg[64];
        #pragma unroll
        for (int l = 0; l < 64; ++l)
            wreg[l] = Whh[(size_t)(seg * 64 + l) * HRc + out];
        hs[tid] = 0.f;
        __syncthreads();
        for (int s = 0; s < 8; ++s){
            float* dst = (s & 1) ? hb0 : hb1;
            if (s > 0){
                const float* src = (s & 1) ? hb1 : hb0;
                if (tid == 0){
                    int guard = 0;
                    while (__hip_atomic_load(cnt, __ATOMIC_ACQUIRE, __HIP_MEMORY_SCOPE_AGENT) < 8 * s
                           && ++guard < (1 << 26)) {}
                }
                __syncthreads();
                hs[tid] = __hip_atomic_load(src + tid, __ATOMIC_RELAXED, __HIP_MEMORY_SCOPE_AGENT);
                __syncthreads();
            }
            int t = k + 1 + s;
            if (t < NTc){
                int k0 = seg * 64;
                float a0 = 0.f, a1 = 0.f, a2 = 0.f, a3 = 0.f;
                #pragma unroll
                for (int kk = 0; kk < 64; kk += 4){
                    a0 += hs[k0 + kk + 0] * wreg[kk + 0];
                    a1 += hs[k0 + kk + 1] * wreg[kk + 1];
                    a2 += hs[k0 + kk + 2] * wreg[kk + 2];
                    a3 += hs[k0 + kk + 3] * wreg[kk + 3];
                }
                psum[seg][o] = (a0 + a1) + (a2 + a3);
                __syncthreads();
                if (seg == 0){
                    float a = 0.f;
                    #pragma unroll
                    for (int r = 0; r < 8; ++r) a += psum[r][o];
                    const float* y = Y + (q * NTc + t) * DYc;
                    float z = bh[out];
                    #pragma unroll
                    for (int d = 0; d < DYc; ++d) z += y[d] * Wih[d * HRc + out];
                    __hip_atomic_store(dst + out, fast_tanh(z + a), __ATOMIC_RELEASE, __HIP_MEMORY_SCOPE_AGENT);
                }
                __syncthreads();
            } else {
                if (seg == 0)
                    __hip_atomic_store(dst + out, hs[out], __ATOMIC_RELEASE, __HIP_MEMORY_SCOPE_AGENT);
                __syncthreads();
            }
            if (tid == 0)
                __hip_atomic_fetch_add(cnt, 1, __ATOMIC_RELEASE, __HIP_MEMORY_SCOPE_AGENT);
        }
    } else if (b < 24){
        // ---- cY: 16 blocks = 4 e-chunks x 4 h-chunks; sleep-spin until RNN done; signal cnt[3] ----
        float* hs2 = (float*)smem;   // 128 floats
        int bb = b - 8;
        int e0 = (bb >> 2) * 128, h = (bb & 3) * 512 + tid;
        if (tid == 0){
            int guard = 0;
            while (__hip_atomic_load(cnt, __ATOMIC_ACQUIRE, __HIP_MEMORY_SCOPE_AGENT) < 64
                   && ++guard < (1 << 20)) {
                __builtin_amdgcn_s_sleep(32);
            }
        }
        __syncthreads();
        if (tid < 128)
            hs2[tid] = __hip_atomic_load(hb0 + e0 + tid, __ATOMIC_RELAXED, __HIP_MEMORY_SCOPE_AGENT);
        __syncthreads();
        float acc = 0.f;
        #pragma unroll 4
        for (int e = 0; e < 128; ++e)
            acc += hs2[e] * Wb1[(size_t)(1 + EXc + e0 + e) * HBc + h];
        atomicAdd(&cY[h], acc);
        __threadfence();
        __syncthreads();
        if (tid == 0)
            __hip_atomic_fetch_add(cnt + 3, 1, __ATOMIC_RELEASE, __HIP_MEMORY_SCOPE_AGENT);
    } else if (b < 152){
        // ---- w12: 128 blocks, 128x128 tiles, K=512 (S=16), double-buffered; signals cnt[1] ----
        short (*Asb)[4096] = (short(*)[4096])smem;
        short (*Bsb)[4096] = (short(*)[4096])(smem + 16384);
        const int KTOT = 16, S = 16;
        int bw = b - 24;
        int wave = tid >> 6, lane = tid & 63;
        bool active = wave < 4;
        int wm = wave >> 1, wn = wave & 1;
        int bx = bw & 15, by = bw >> 4;
        int quad = lane >> 4, llo = lane & 15;
        f32x4 acc[4][4];
        #pragma unroll
        for (int i = 0; i < 4; ++i)
            #pragma unroll
            for (int j = 0; j < 4; ++j) acc[i][j] = (f32x4){0.f, 0.f, 0.f, 0.f};
        if (active) stage32(Wx2a, Wb1p, Asb[0], Bsb[0], by * 8, bx * 8, 0, KTOT, wave, lane);
        for (int s = 0; s < S; ++s){
            int buf = s & 1;
            __syncthreads();
            if (active && s + 1 < S)
                stage32(Wx2a, Wb1p, Asb[buf ^ 1], Bsb[buf ^ 1], by * 8, bx * 8, s + 1, KTOT, wave, lane);
            if (active) STAGE_COMPUTE(Asb[buf], Bsb[buf]);
        }
        if (active){
            // write W12[c][h] into gemm slab layout: [slab=h>>8][kt=c>>6][chunk=((h>>4)&15)*2+((c>>5)&1)]
            #pragma unroll
            for (int j = 0; j < 4; ++j){
                int h = bx * 128 + wn * 64 + j * 16 + llo;
                #pragma unroll
                for (int i = 0; i < 4; ++i){
                    #pragma unroll
                    for (int r = 0; r < 4; ++r){
                        int c = by * 128 + wm * 64 + i * 16 + quad * 4 + r;
                        size_t idx = ((((size_t)(h >> 8) * 16 + (c >> 6)) * 32)
                                      + ((h >> 4) & 15) * 2 + ((c >> 5) & 1)) * 512
                                   + (size_t)(((c >> 3) & 3) * 16 + (h & 15)) * 8 + (c & 7);
                        W12p[idx] = f2bf(acc[i][j][r]);
                    }
                }
            }
        }
        __threadfence();
        __syncthreads();
        if (tid == 0)
            __hip_atomic_fetch_add(cnt + 1, 1, __ATOMIC_RELEASE, __HIP_MEMORY_SCOPE_AGENT);
    } else if (b < 216){
        // ---- T1p: pack T1 (256x1024) into slab layout (64 blocks x 512 threads); signals cnt[2] ----
        size_t grp = (size_t)(b - 152) * 512 + tid;   // 32768 groups
        int lane = (int)(grp & 63);
        size_t t2 = grp >> 6;                         // kt*32 + mt*2 + kk
        int kk = (int)(t2 & 1);
        int mt = (int)((t2 >> 1) & 15);
        int kt = (int)(t2 >> 5);
        int mloc = mt * 16 + (lane & 15);
        int c0 = kt * 64 + kk * 32 + ((lane >> 4) << 3);
        const float* t1r = T1 + (size_t)mloc * HXc + c0;
        short o8[8];
        #pragma unroll
        for (int i = 0; i < 8; ++i) o8[i] = f2bf(t1r[i]);
        *(bf16x8*)(T1p + grp * 8) = *(bf16x8*)o8;
        __threadfence();
        __syncthreads();
        if (tid == 0)
            __hip_atomic_fetch_add(cnt + 2, 1, __ATOMIC_RELEASE, __HIP_MEMORY_SCOPE_AGENT);
    } else if (b < 280){
        // ---- tbgemm: TB = tanh(T1@W12 + (tk+tau)*Wb1[0] + cY + c0row); 64x128 tiles ----
        short (*tA)[2048] = (short(*)[2048])smem;            // [2][2048]
        short (*tB)[4096] = (short(*)[4096])(smem + 8192);   // [2][4096]
        int bt = b - 216;
        int wave = tid >> 6, lane = tid & 63;
        bool active = wave < 4;
        int wn = wave & 3;
        int bmT = bt & 3, bnT = bt >> 2;
        int quad = lane >> 4, llo = lane & 15;
        int slabB = bnT >> 1, halfB = bnT & 1;
        const short* Bb = W12p + (size_t)slabB * 16 * 32 * 512;
        // phase 1: wait for w12 (cnt[1]==128) + T1p (cnt[2]==64)
        if (tid == 0){
            int guard = 0;
            while ((__hip_atomic_load(cnt + 1, __ATOMIC_ACQUIRE, __HIP_MEMORY_SCOPE_AGENT) < 128 ||
                    __hip_atomic_load(cnt + 2, __ATOMIC_ACQUIRE, __HIP_MEMORY_SCOPE_AGENT) < 64)
                   && ++guard < (1 << 20)) {
                __builtin_amdgcn_s_sleep(32);
            }
        }
        __syncthreads();
        f32x4 acc[4][2];
        #pragma unroll
        for (int i = 0; i < 4; ++i)
            #pragma unroll
            for (int j = 0; j < 2; ++j) acc[i][j] = (f32x4){0.f, 0.f, 0.f, 0.f};
#define TBST(s, buf) if (active){ int kt_ = (s) >> 1, kk_ = (s) & 1;                               \
        _Pragma("unroll") for (int c = 0; c < 3; ++c){                                             \
            int ci = wn * 3 + c;                                                                   \
            if (ci < 4){                                                                           \
                size_t ch = (size_t)kt_ * 32 + ((bmT * 4 + ci) << 1) + kk_;                        \
                gld_lds16(T1p + ch * 512 + lane * 8, tA[buf] + ci * 512);                          \
            } else {                                                                               \
                int t = ci - 4;                                                                    \
                size_t ch = (size_t)kt_ * 32 + ((halfB * 8 + t) << 1) + kk_;                       \
                gld_lds16(Bb + ch * 512 + lane * 8, tB[buf] + t * 512);                            \
            } } }
        TBST(0, 0);
        for (int s = 0; s < 32; ++s){
            int buf = s & 1;
            __syncthreads();
            if (s + 1 < 32) TBST(s + 1, buf ^ 1);
            if (active){
                bf16x8 af[4], bfr[2];
                #pragma unroll
                for (int i = 0; i < 4; ++i) af[i] = *(const bf16x8*)(tA[buf] + i * 512 + lane * 8);
                #pragma unroll
                for (int j = 0; j < 2; ++j) bfr[j] = *(const bf16x8*)(tB[buf] + (wn * 2 + j) * 512 + lane * 8);
                #pragma unroll
                for (int i = 0; i < 4; ++i)
                    #pragma unroll
                    for (int j = 0; j < 2; ++j)
                        acc[i][j] = __builtin_amdgcn_mfma_f32_16x16x32_bf16(af[i], bfr[j], acc[i][j], 0, 0, 0);
            }
        }
#undef TBST
        // phase 2: wait for cY (cnt[3]==16), then epilogue
        if (tid == 0){
            int guard = 0;
            while (__hip_atomic_load(cnt + 3, __ATOMIC_ACQUIRE, __HIP_MEMORY_SCOPE_AGENT) < 16
                   && ++guard < (1 << 20)) {
                __builtin_amdgcn_s_sleep(32);
            }
        }
        __syncthreads();
        if (active){
            float tk = times_t[kptr[0]];
            float cyv[2], c0v[2], wbv[2];
            #pragma unroll
            for (int j = 0; j < 2; ++j){
                int h = bnT * 128 + wn * 32 + j * 16 + llo;
                cyv[j] = __hip_atomic_load(cY + h, __ATOMIC_RELAXED, __HIP_MEMORY_SCOPE_AGENT);
                c0v[j] = c0row[h];
                wbv[j] = Wb1[h];
            }
            #pragma unroll
            for (int i = 0; i < 4; ++i){
                #pragma unroll
                for (int r = 0; r < 4; ++r){
                    int m = bmT * 64 + i * 16 + quad * 4 + r;
                    float tv = tk + times_tau[m];
                    #pragma unroll
                    for (int j = 0; j < 2; ++j){
                        int h = bnT * 128 + wn * 32 + j * 16 + llo;
                        float z = acc[i][j][r] + tv * wbv[j] + cyv[j] + c0v[j];
                        TB[(size_t)m * HBc + h] = fast_tanh(z);
                    }
                }
            }
        }
    } else {
        // ---- act_delta: A1p = bf16(tanh(XW+SW[j]) - T1), slab layout (4096 blocks x 512 threads) ----
        size_t grp = (size_t)(b - 280) * 512 + tid;  // 2,097,152 groups
        int lane = (int)(grp & 63);
        size_t t2 = grp >> 6;
        int kk = (int)(t2 & 1);
        int mt = (int)((t2 >> 1) & 15);
        int kt = (int)((t2 >> 5) & 15);
        int j  = (int)(t2 >> 9);             // 0..63
        int mloc = mt * 16 + (lane & 15);
        int c0 = kt * 64 + kk * 32 + ((lane >> 4) << 3);
        const float* xwr = XW + (size_t)mloc * HXc + c0;
        const float* t1r = T1 + (size_t)mloc * HXc + c0;
        const float* swr = SW + (size_t)j * HXc + c0;
        short o8[8];
        #pragma unroll
        for (int i = 0; i < 8; ++i)
            o8[i] = f2bf(fast_tanh(xwr[i] + swr[i]) - t1r[i]);
        *(bf16x8*)(A1p + grp * 8) = *(bf16x8*)o8;
    }
}

// ================== gemm_big: 256x256 tile, BK=64, 8-wave, 8-phase counted-vmcnt (R9/R12-verbatim) ==================
// Dz2 = A1p(16384x1024) @ W12p(1024x2048), fused tanh-delta epilogue. grid (64,8), 512 threads.
// LDS 128 KiB (1 block/CU). 88.3-90us, 6x confirmed — frozen.
//   ph1:T+1.A0  ph2:T+1.A1  ph3:T+2.B0  ph4:T+2.B1+vmcnt(4)
//   ph5:T+2.A0  ph6:T+2.A1  ph7:T+3.B0  ph8:T+3.B1+vmcnt(4)
__device__ __forceinline__ void stage_half(const short* __restrict__ base, short* lbase,
                                           int wave, int lane){
    const short* s = base + (size_t)(wave * 2) * 512 + lane * 8;
    short* d = lbase + (wave * 2) * 512;
    gld_lds16(s, d);
    gld_lds16(s + 512, d + 512);
}

__global__ __launch_bounds__(512, 2) void gemm_big(
    const short* __restrict__ Ap, const short* __restrict__ Bp,
    const float* __restrict__ TB, const float* __restrict__ wrow,
    float* __restrict__ dacc){
    __shared__ __align__(16) short As[2][16384];
    __shared__ __align__(16) short Bs[2][16384];
    __shared__ float redn[256];
    int tid = threadIdx.x;
    int wave = tid >> 6, lane = tid & 63;
    int wm = wave >> 2, wn = wave & 3;
    int bm = blockIdx.x, bn = blockIdx.y;
    int quad = lane >> 4, llo = lane & 15;
    const short* Ab = Ap + (size_t)bm * 16 * 32 * 512;   // 256-row slab: 16 ktiles x 32 chunks x 1KB
    const short* Bb = Bp + (size_t)bn * 16 * 32 * 512;   // 256-col slab

    f32x4 acc[8][4];
    #pragma unroll
    for (int i = 0; i < 8; ++i)
        #pragma unroll
        for (int j = 0; j < 4; ++j) acc[i][j] = (f32x4){0.f, 0.f, 0.f, 0.f};

    bf16x8 af[4][2];
    bf16x8 bfr[4][2];

#define BARX() __builtin_amdgcn_s_barrier()
#define GATE4() asm volatile("s_waitcnt vmcnt(4)" ::: "memory")
#define GATE0() asm volatile("s_waitcnt vmcnt(0)" ::: "memory")
#define STAGE_A(kt, h, buf) stage_half(Ab + ((size_t)(kt) * 32 + (h) * 16) * 512, &As[buf][(h) * 16 * 512], wave, lane)
#define STAGE_B(kt, h, buf) stage_half(Bb + ((size_t)(kt) * 32 + (h) * 16) * 512, &Bs[buf][(h) * 16 * 512], wave, lane)
#define RD_A(buf, ib) { _Pragma("unroll") for (int i_ = 0; i_ < 4; ++i_)                                   \
        _Pragma("unroll") for (int k_ = 0; k_ < 2; ++k_)                                                   \
            af[i_][k_] = *(const bf16x8*)&As[buf][(((wm * 8 + (ib) + i_) * 2 + k_) * 512) + lane * 8]; }
#define RD_B(buf, jb) { _Pragma("unroll") for (int j_ = 0; j_ < 2; ++j_)                                   \
        _Pragma("unroll") for (int k_ = 0; k_ < 2; ++k_)                                                   \
            bfr[(jb) + j_][k_] = *(const bf16x8*)&Bs[buf][(((wn * 4 + (jb) + j_) * 2 + k_) * 512) + lane * 8]; }
#define MFMA16(mb, nb) { _Pragma("unroll") for (int k_ = 0; k_ < 2; ++k_)                                  \
        _Pragma("unroll") for (int i_ = 0; i_ < 4; ++i_)                                                   \
        _Pragma("unroll") for (int j_ = 0; j_ < 2; ++j_)                                                   \
            acc[(mb) + i_][(nb) + j_] = __builtin_amdgcn_mfma_f32_16x16x32_bf16(                           \
                af[i_][k_], bfr[(nb) + j_][k_], acc[(mb) + i_][(nb) + j_], 0, 0, 0); }
#define PH(reads, stage, mfma, gate) do {                                                                  \
        reads; stage;                                                                                      \
        BARX();                                                                                            \
        __builtin_amdgcn_s_setprio(1); mfma; __builtin_amdgcn_s_setprio(0);                                \
        gate;                                                                                              \
        BARX(); } while (0)

    // prologue: tile0 (B then A) + tile1 B; vmcnt(4) -> tile0 fully resident, 1.B in flight
    STAGE_B(0, 0, 0); STAGE_B(0, 1, 0);
    STAGE_A(0, 0, 0); STAGE_A(0, 1, 0);
    STAGE_B(1, 0, 1); STAGE_B(1, 1, 1);
    GATE4();
    BARX();

    for (int T = 0; T < 14; T += 2){
        PH(RD_A(0, 0); RD_B(0, 0), STAGE_A(T + 1, 0, 1), MFMA16(0, 0), );
        PH(RD_B(0, 2),             STAGE_A(T + 1, 1, 1), MFMA16(0, 2), );
        PH(RD_A(0, 4),             STAGE_B(T + 2, 0, 0), MFMA16(4, 0), );
        PH(                      , STAGE_B(T + 2, 1, 0), MFMA16(4, 2), GATE4());
        PH(RD_A(1, 0); RD_B(1, 0), STAGE_A(T + 2, 0, 0), MFMA16(0, 0), );
        PH(RD_B(1, 2),             STAGE_A(T + 2, 1, 0), MFMA16(0, 2), );
        PH(RD_A(1, 4),             STAGE_B(T + 3, 0, 1), MFMA16(4, 0), );
        PH(                      , STAGE_B(T + 3, 1, 1), MFMA16(4, 2), GATE4());
    }
    // peeled final iteration: T=14 (tiles 14,15); only 15.A0/A1 remain to stage
    PH(RD_A(0, 0); RD_B(0, 0), STAGE_A(15, 0, 1), MFMA16(0, 0), );
    PH(RD_B(0, 2),             STAGE_A(15, 1, 1), MFMA16(0, 2), );
    PH(RD_A(0, 4),           ,                    MFMA16(4, 0), );
    PH(                      , ,                  MFMA16(4, 2), GATE0());
    PH(RD_A(1, 0); RD_B(1, 0), ,                  MFMA16(0, 0), );
    PH(RD_B(1, 2),             ,                  MFMA16(0, 2), );
    PH(RD_A(1, 4),             ,                  MFMA16(4, 0), );
    PH(                      , ,                  MFMA16(4, 2), );

#undef PH
#undef MFMA16
#undef RD_B
#undef RD_A
#undef STAGE_B
#undef STAGE_A
#undef GATE0
#undef GATE4
#undef BARX

    // fused epilogue: tanh(zb+dz)-tanh(zb) = tdz*(1-tb^2)/(1+tb*tdz), weighted by wrow, reduce over m
    int nj[4];
    #pragma unroll
    for (int j = 0; j < 4; ++j) nj[j] = bn * 256 + wn * 64 + j * 16 + llo;
    float part[4] = {};
    #pragma unroll
    for (int i = 0; i < 8; ++i){
        #pragma unroll
        for (int r = 0; r < 4; ++r){
            int m = bm * 256 + wm * 128 + i * 16 + quad * 4 + r;
            float wr = wrow[m];
            const float* trow = TB + (size_t)(m & 255) * HBc;
            #pragma unroll
            for (int j = 0; j < 4; ++j){
                float tb  = trow[nj[j]];
                float tdz = fast_tanh(acc[i][j][r]);
                float num = tdz * (1.0f - tb * tb);
                float den = 1.0f + tb * tdz;
                part[j] += wr * num * __builtin_amdgcn_rcpf(den);
            }
        }
    }
    #pragma unroll
    for (int j = 0; j < 4; ++j){
        part[j] += __shfl_xor(part[j], 16);
        part[j] += __shfl_xor(part[j], 32);
    }
    if (tid < 256) redn[tid] = 0.f;
    __syncthreads();
    if (quad == 0){
        #pragma unroll
        for (int j = 0; j < 4; ++j)
            atomicAdd(&redn[wn * 64 + j * 16 + llo], part[j]);
    }
    __syncthreads();
    if (tid < 256) atomicAdd(&dacc[bn * 256 + tid], redn[tid]);
}

// ---------------- si = dacc @ Wb2, split over 8 blocks (out pre-zeroed in prep) ----------------
__global__ void out_kernel(const float* __restrict__ dacc, const float* __restrict__ Wb2,
                           float* __restrict__ out){
    __shared__ float red[4][64];
    int tid = threadIdx.x;
    int g = tid & 63, seg = tid >> 6;
    int h0 = blockIdx.x * 256 + seg * 64;
    float s = 0.f;
    #pragma unroll 8
    for (int hh = 0; hh < 64; ++hh)
        s += dacc[h0 + hh] * Wb2[(size_t)(h0 + hh) * GOUTc + g];
    red[seg][g] = s;
    __syncthreads();
    if (tid < 64)
        atomicAdd(&out[tid], red[0][tid] + red[1][tid] + red[2][tid] + red[3][tid]);
}

extern "C" void kernel_launch(void* const* d_in, const int* in_sizes, int n_in,
                              void* d_out, int out_size, void* d_ws, size_t ws_size,
                              hipStream_t stream){
    const float* X         = (const float*)d_in[0];
    const float* Y         = (const float*)d_in[1];
    const float* R         = (const float*)d_in[2];
    const float* stoich    = (const float*)d_in[3];
    const float* times_t   = (const float*)d_in[4];
    const float* times_tau = (const float*)d_in[5];
    const float* Wx1 = (const float*)d_in[6];
    const float* bx1 = (const float*)d_in[7];
    const float* Wx2 = (const float*)d_in[8];
    const float* bx2 = (const float*)d_in[9];
    const float* Wih = (const float*)d_in[10];
    const float* Whh = (const float*)d_in[11];
    const float* bh  = (const float*)d_in[12];
    const float* Wb1 = (const float*)d_in[13];
    const float* bb1 = (const float*)d_in[14];
    const float* Wb2 = (const float*)d_in[15];
    // d_in[16] = bb2: cancels in (nn_disp - nn), unused
    const int* kp  = (const int*)d_in[17];
    const int* kpp = (const int*)d_in[18];
    const int* qp  = (const int*)d_in[19];
    const int* qpp = (const int*)d_in[20];
    float* out = (float*)d_out;

    float* ws     = (float*)d_ws;
    float* hb0    = ws;                        // 512
    float* hb1    = ws + 512;                  // 512
    float* cY     = ws + 1024;                 // 2048
    float* dacc   = ws + 3072;                 // 2048
    float* wrow   = ws + 5120;                 // 64*256 = 16384
    float* SW     = ws + 21504;                // 64*1024 = 65536
    float* XW     = ws + 87040;                // 256*1024 = 262144
    float* T1     = ws + 349184;               // 256*1024 = 262144
    float* c0row  = ws + 611328;               // 2048
    float* TB     = ws + 742400;               // 256*2048 = 524288
    short* T1p    = (short*)(ws + 1266688);    // 256*1024 bf16 = 131,072 float slots
    short* A1p    = (short*)(ws + 1790976);    // 16384*1024 bf16 = 8,388,608 float slots
    short* Wx2a   = (short*)(ws + 10179584);   // 1024*512 bf16 = 262,144 float slots
    short* Wb1p   = (short*)(ws + 10441728);   // 512*2048 bf16 = 524,288 float slots
    short* W12p   = (short*)(ws + 10966016);   // 1024*2048 bf16 = 1,048,576 float slots
    int*   cnt    = (int*)(ws + 12014592);     // 4 ints: rnn-step, w12done, t1pdone, cydone

    prep_kernel<<<2177, 256, 0, stream>>>(stoich, Wx1, Wx2, Wb1, X, R, bx1, bx2, bb1, kpp, qpp,
                                          SW, Wx2a, Wb1p, XW, T1, wrow, hb0, dacc, out,
                                          c0row, cY, cnt);
    mid_kernel <<<4376, 512, 0, stream>>>(XW, T1, SW, A1p, T1p, Y, Wih, Whh, bh, Wb1,
                                          kp, qp, hb0, hb1, cnt, cY, Wx2a, Wb1p, W12p,
                                          c0row, times_t, times_tau, TB);
    gemm_big   <<<dim3(64, 8), 512, 0, stream>>>(A1p, W12p, TB, wrow, dacc);
    out_kernel <<<8,   256, 0, stream>>>(dacc, Wb2, out);
}

// Round 14
// 276.406 us; speedup vs baseline: 1.0978x; 1.0978x over previous
//
#include <hip/hip_runtime.h>
#include <math.h>

// Shapes (fixed by the reference)
#define DXc   16
#define MRc   64
#define MBARc 256
#define NTc   9
#define DYc   8
#define HXc   1024
#define EXc   512
#define HRc   512
#define HBc   2048
#define GOUTc 64
#define TOTc  2049   // (NT-1)*MBAR + 1

using bf16x8 = __attribute__((ext_vector_type(8))) short;
using f32x4  = __attribute__((ext_vector_type(4))) float;

typedef unsigned int u32;
typedef u32 __attribute__((address_space(1))) gbl_u32;
typedef u32 __attribute__((address_space(3))) lds_u32;

__device__ __forceinline__ float fast_tanh(float x){
    float e = __expf(2.0f * x);
    return 1.0f - 2.0f / (e + 1.0f);
}

// fp32 -> bf16 round-to-nearest-even (bit pattern in a short)
__device__ __forceinline__ short f2bf(float f){
    unsigned u = __builtin_bit_cast(unsigned, f);
    u = (u + 0x7FFFu + ((u >> 16) & 1u)) >> 16;
    return (short)u;
}

// async global->LDS: each lane loads 16 B from g + lane*16; LDS dest = base + lane*16
__device__ __forceinline__ void gld_lds16(const short* g, short* l){
    __builtin_amdgcn_global_load_lds((const gbl_u32*)g, (lds_u32*)l, 16, 0, 0);
}

// ---------------- prep: SW + packs + XW/T1 + wrow + c0row(64-block parallel) + inits ----------------
// grid 2177 x 256
__global__ void prep_kernel(const float* __restrict__ stoich, const float* __restrict__ Wx1,
                            const float* __restrict__ Wx2, const float* __restrict__ Wb1,
                            const float* __restrict__ X, const float* __restrict__ R,
                            const float* __restrict__ bx1, const float* __restrict__ bx2,
                            const float* __restrict__ bb1,
                            const int* kpptr, const int* qpptr,
                            float* __restrict__ SW, short* __restrict__ Wx2a,
                            short* __restrict__ Wb1p, float* __restrict__ XW,
                            float* __restrict__ T1, float* __restrict__ wrow,
                            float* __restrict__ hb0, float* __restrict__ dacc,
                            float* __restrict__ outz, float* __restrict__ c0row,
                            float* __restrict__ cY, int* __restrict__ cnt){
    int b = blockIdx.x, tid = threadIdx.x;
    if (b < 256){
        // SW[j][c] = stoich[:,j] @ Wx1
        int idx = b * 256 + tid;
        int j = idx >> 10, c = idx & 1023;
        float acc = 0.f;
        #pragma unroll
        for (int d = 0; d < DXc; ++d) acc += stoich[d * MRc + j] * Wx1[d * HXc + c];
        SW[idx] = acc;
    } else if (b < 512){
        // pack Wx2 (1024x512) into MFMA A-fragment order (M=c rows, K=e), KTOT=16, layout [chunk][kt][512]
        size_t grp = (size_t)(b - 256) * 256 + tid;    // 65536 groups
        int lane = grp & 63;
        size_t t2 = grp >> 6;
        int kt = t2 & 15, mt = t2 >> 4;                // mt 0..63
        int c  = mt * 16 + (lane & 15);
        int e0 = kt * 32 + ((lane >> 4) << 3);
        short o8[8];
        #pragma unroll
        for (int jj = 0; jj < 8; ++jj) o8[jj] = f2bf(Wx2[(size_t)c * EXc + e0 + jj]);
        *(bf16x8*)(Wx2a + grp * 8) = *(bf16x8*)o8;
    } else if (b < 1024){
        // pack Wb1 rows 1..512 (512x2048) into B-fragment order, KTOT=16, layout [chunk][kt][512]
        size_t grp = (size_t)(b - 512) * 256 + tid;
        int lane = grp & 63;
        size_t t2 = grp >> 6;
        int kt = t2 & 15, nt = t2 >> 4;
        int n  = nt * 16 + (lane & 15);
        int k0 = kt * 32 + ((lane >> 4) << 3);
        short o8[8];
        #pragma unroll
        for (int jj = 0; jj < 8; ++jj) o8[jj] = f2bf(Wb1[(size_t)(1 + k0 + jj) * HBc + n]);
        *(bf16x8*)(Wb1p + grp * 8) = *(bf16x8*)o8;
    } else if (b < 2048){
        // XW = Xbase@Wx1 + bx1 ; T1 = tanh(XW)
        int idx = (b - 1024) * 256 + tid;
        int m = idx >> 10, c = idx & 1023;
        int base = kpptr[0] * MBARc;
        const float* xr = X + ((size_t)qpptr[0] * TOTc + base + m) * DXc;
        float acc = bx1[c];
        #pragma unroll
        for (int d = 0; d < DXc; ++d) acc += xr[d] * Wx1[d * HXc + c];
        XW[idx] = acc;
        T1[idx] = fast_tanh(acc);
    } else if (b < 2112){
        // wrow[j*256+m] = valid(j,m) * R_delta
        int j = b - 2048, m = tid;
        int base = kpptr[0] * MBARc;
        int qp = qpptr[0];
        const float* xr = X + ((size_t)qp * TOTc + base + m) * DXc;
        bool valid = true;
        #pragma unroll
        for (int d = 0; d < DXc; ++d) valid = valid && (xr[d] + stoich[d * MRc + j] >= 0.f);
        size_t rb = (size_t)qp * TOTc * MRc;
        float rd = R[rb + (size_t)(base + 1 + m) * MRc + j] - R[rb + (size_t)(base + m) * MRc + j];
        wrow[j * MBARc + m] = valid ? rd : 0.f;
    } else if (b == 2112){
        hb0[tid] = 0.f; hb0[tid + 256] = 0.f;
        #pragma unroll
        for (int l = 0; l < 8; ++l) dacc[tid + l * 256] = 0.f;
        #pragma unroll
        for (int l = 0; l < 8; ++l) cY[tid + l * 256] = bb1[tid + l * 256];
        if (tid < GOUTc) outz[tid] = 0.f;
        if (tid == 0){ cnt[0] = 0; cnt[1] = 0; cnt[2] = 0; cnt[3] = 0; }
    } else {
        // c0row[h] = bx2 @ Wb1[1:513, h]; 64 blocks x 32 h, 8 e-segments reduced in LDS
        __shared__ float cps[32][8];
        int bb = b - 2113;                  // 0..63
        int hl = tid & 31, sg = tid >> 5;   // 32 h x 8 segs
        int h = bb * 32 + hl, e0 = sg * 64;
        float a = 0.f;
        #pragma unroll 8
        for (int e = 0; e < 64; ++e)
            a += bx2[e0 + e] * Wb1[(size_t)(1 + e0 + e) * HBc + h];
        cps[hl][sg] = a;
        __syncthreads();
        if (sg == 0){
            float s = 0.f;
            #pragma unroll
            for (int r = 0; r < 8; ++r) s += cps[hl][r];
            c0row[h] = s;
        }
    }
}

// ---- MFMA helpers (4x4 grid, used by w12) ----
#define MMGRID(aa, bb) {                                                       \
    _Pragma("unroll") for (int i_ = 0; i_ < 4; ++i_)                           \
        _Pragma("unroll") for (int j_ = 0; j_ < 4; ++j_)                       \
            acc[i_][j_] = __builtin_amdgcn_mfma_f32_16x16x32_bf16(aa[i_], bb[j_], acc[i_][j_], 0, 0, 0); }

// stage BK=32 (1 kt) from [chunk][kt][512] layout: 8 A + 8 B chunks of 1 KB; waves 0..3 stage 4 each
__device__ __forceinline__ void stage32(const short* __restrict__ Ap, const short* __restrict__ Bp,
                                        short* As, short* Bs,
                                        int at0, int bt0, int s, int KTOT, int wave, int lane){
    #pragma unroll
    for (int c = 0; c < 4; ++c){
        int ci = wave * 4 + c;            // 0..15
        int half = ci >> 3;               // 0 = A, 1 = B
        int t    = ci & 7;
        const short* src = half ? (Bp + ((size_t)(bt0 + t) * KTOT + s) * 512 + lane * 8)
                                : (Ap + ((size_t)(at0 + t) * KTOT + s) * 512 + lane * 8);
        short* dst = (half ? Bs : As) + t * 512;
        gld_lds16(src, dst);
    }
}

#define STAGE_COMPUTE(As, Bs) {                                                       \
    bf16x8 af[4], bfr[4];                                                             \
    _Pragma("unroll") for (int i_ = 0; i_ < 4; ++i_)                                  \
        af[i_] = *(const bf16x8*)((As) + ((wm * 4 + i_) * 512) + lane * 8);           \
    _Pragma("unroll") for (int j_ = 0; j_ < 4; ++j_)                                  \
        bfr[j_] = *(const bf16x8*)((Bs) + ((wn * 4 + j_) * 512) + lane * 8);          \
    MMGRID(af, bfr); }

// ================ mid: RNN(XCD-colocated) + cY + w12 + T1p + act_delta, ONE dispatch ================
// Role mapping (hardware round-robins block id % 8 -> XCD):
//   b in {0,8,...,56} (b&7==0, b<64): RNN block rb=b>>3  -> ALL land on XCD 0, so the 8-step
//     cnt/hb rendezvous atomics stay L2-local (vs cross-XCD with ids 0..7). Scheduling-only change;
//     correctness unaffected (agent-scope atomics are device-coherent regardless of placement).
//   other b<64 (56 blocks): act_delta (act_idx = b - (b>>3) - 1)
//   [64,80):   cY (sleep-spin cnt[0]==64)
//   [80,208):  w12 gemm, double-buffered 32KB (waves 0..3 active)
//   [208,272): T1p pack
//   [272,4312): act_delta (act_idx = 56 + b - 272); total act = 4096
// Union LDS = 32 KB -> act blocks run 4 blocks/CU; RNN chain hides under act (R10/R12 proven).
__global__ __launch_bounds__(512) void mid_kernel(
    const float* __restrict__ XW, const float* __restrict__ T1,
    const float* __restrict__ SW, short* __restrict__ A1p, short* __restrict__ T1p,
    const float* __restrict__ Y, const float* __restrict__ Wih,
    const float* __restrict__ Whh, const float* __restrict__ bh,
    const float* __restrict__ Wb1,
    const int* kptr, const int* qptr,
    float* __restrict__ hb0, float* __restrict__ hb1,
    int* __restrict__ cnt, float* __restrict__ cY,
    const short* __restrict__ Wx2a, const short* __restrict__ Wb1p,
    short* __restrict__ W12p){
    __shared__ __align__(16) char smem[32768];   // union: rnn 4K | cY 0.5K | w12 32K
    int b = blockIdx.x, tid = threadIdx.x;
    if (b < 64 && (b & 7) == 0){
        // ---- RNN: Whh[:, out] segment in registers; 8 blocks (one per CU on XCD 0), cnt-gated ----
        float* hs = (float*)smem;                              // 512
        float (*psum)[64] = (float(*)[64])(smem + 2048);       // [8][64]
        int rb = b >> 3;                                       // 0..7
        int o = tid & 63, seg = tid >> 6;
        int out = rb * 64 + o;
        int k = kptr[0], q = qptr[0];
        float wreg[64];
        #pragma unroll
        for (int l = 0; l < 64; ++l)
            wreg[l] = Whh[(size_t)(seg * 64 + l) * HRc + out];
        hs[tid] = 0.f;
        __syncthreads();
        for (int s = 0; s < 8; ++s){
            float* dst = (s & 1) ? hb0 : hb1;
            if (s > 0){
                const float* src = (s & 1) ? hb1 : hb0;
                if (tid == 0){
                    int guard = 0;
                    while (__hip_atomic_load(cnt, __ATOMIC_ACQUIRE, __HIP_MEMORY_SCOPE_AGENT) < 8 * s
                           && ++guard < (1 << 26)) {}
                }
                __syncthreads();
                hs[tid] = __hip_atomic_load(src + tid, __ATOMIC_RELAXED, __HIP_MEMORY_SCOPE_AGENT);
                __syncthreads();
            }
            int t = k + 1 + s;
            if (t < NTc){
                int k0 = seg * 64;
                float a0 = 0.f, a1 = 0.f, a2 = 0.f, a3 = 0.f;
                #pragma unroll
                for (int kk = 0; kk < 64; kk += 4){
                    a0 += hs[k0 + kk + 0] * wreg[kk + 0];
                    a1 += hs[k0 + kk + 1] * wreg[kk + 1];
                    a2 += hs[k0 + kk + 2] * wreg[kk + 2];
                    a3 += hs[k0 + kk + 3] * wreg[kk + 3];
                }
                psum[seg][o] = (a0 + a1) + (a2 + a3);
                __syncthreads();
                if (seg == 0){
                    float a = 0.f;
                    #pragma unroll
                    for (int r = 0; r < 8; ++r) a += psum[r][o];
                    const float* y = Y + (q * NTc + t) * DYc;
                    float z = bh[out];
                    #pragma unroll
                    for (int d = 0; d < DYc; ++d) z += y[d] * Wih[d * HRc + out];
                    __hip_atomic_store(dst + out, fast_tanh(z + a), __ATOMIC_RELEASE, __HIP_MEMORY_SCOPE_AGENT);
                }
                __syncthreads();
            } else {
                if (seg == 0)
                    __hip_atomic_store(dst + out, hs[out], __ATOMIC_RELEASE, __HIP_MEMORY_SCOPE_AGENT);
                __syncthreads();
            }
            if (tid == 0)
                __hip_atomic_fetch_add(cnt, 1, __ATOMIC_RELEASE, __HIP_MEMORY_SCOPE_AGENT);
        }
    } else if (b >= 64 && b < 80){
        // ---- cY: 16 blocks = 4 e-chunks x 4 h-chunks; SLEEP-spin until RNN done (cnt==64) ----
        float* hs2 = (float*)smem;   // 128 floats
        int bb = b - 64;
        int e0 = (bb >> 2) * 128, h = (bb & 3) * 512 + tid;
        if (tid == 0){
            int guard = 0;
            while (__hip_atomic_load(cnt, __ATOMIC_ACQUIRE, __HIP_MEMORY_SCOPE_AGENT) < 64
                   && ++guard < (1 << 20)) {
                __builtin_amdgcn_s_sleep(32);
            }
        }
        __syncthreads();
        if (tid < 128)
            hs2[tid] = __hip_atomic_load(hb0 + e0 + tid, __ATOMIC_RELAXED, __HIP_MEMORY_SCOPE_AGENT);
        __syncthreads();
        float acc = 0.f;
        #pragma unroll 4
        for (int e = 0; e < 128; ++e)
            acc += hs2[e] * Wb1[(size_t)(1 + EXc + e0 + e) * HBc + h];
        atomicAdd(&cY[h], acc);
    } else if (b >= 80 && b < 208){
        // ---- w12: 128 blocks, 128x128 tiles, K=512 (S=16), double-buffered; waves 0..3 active ----
        short (*Asb)[4096] = (short(*)[4096])smem;
        short (*Bsb)[4096] = (short(*)[4096])(smem + 16384);
        const int KTOT = 16, S = 16;
        int bw = b - 80;
        int wave = tid >> 6, lane = tid & 63;
        bool active = wave < 4;
        int wm = wave >> 1, wn = wave & 1;
        int bx = bw & 15, by = bw >> 4;
        int quad = lane >> 4, llo = lane & 15;
        f32x4 acc[4][4];
        #pragma unroll
        for (int i = 0; i < 4; ++i)
            #pragma unroll
            for (int j = 0; j < 4; ++j) acc[i][j] = (f32x4){0.f, 0.f, 0.f, 0.f};
        if (active) stage32(Wx2a, Wb1p, Asb[0], Bsb[0], by * 8, bx * 8, 0, KTOT, wave, lane);
        for (int s = 0; s < S; ++s){
            int buf = s & 1;
            __syncthreads();
            if (active && s + 1 < S)
                stage32(Wx2a, Wb1p, Asb[buf ^ 1], Bsb[buf ^ 1], by * 8, bx * 8, s + 1, KTOT, wave, lane);
            if (active) STAGE_COMPUTE(Asb[buf], Bsb[buf]);
        }
        if (active){
            // write W12[c][h] into gemm slab layout: [slab=h>>8][kt=c>>6][chunk=((h>>4)&15)*2+((c>>5)&1)]
            #pragma unroll
            for (int j = 0; j < 4; ++j){
                int h = bx * 128 + wn * 64 + j * 16 + llo;
                #pragma unroll
                for (int i = 0; i < 4; ++i){
                    #pragma unroll
                    for (int r = 0; r < 4; ++r){
                        int c = by * 128 + wm * 64 + i * 16 + quad * 4 + r;
                        size_t idx = ((((size_t)(h >> 8) * 16 + (c >> 6)) * 32)
                                      + ((h >> 4) & 15) * 2 + ((c >> 5) & 1)) * 512
                                   + (size_t)(((c >> 3) & 3) * 16 + (h & 15)) * 8 + (c & 7);
                        W12p[idx] = f2bf(acc[i][j][r]);
                    }
                }
            }
        }
    } else if (b >= 208 && b < 272){
        // ---- T1p: pack T1 (256x1024) into slab layout (64 blocks x 512 threads) ----
        size_t grp = (size_t)(b - 208) * 512 + tid;   // 32768 groups
        int lane = (int)(grp & 63);
        size_t t2 = grp >> 6;                         // kt*32 + mt*2 + kk
        int kk = (int)(t2 & 1);
        int mt = (int)((t2 >> 1) & 15);
        int kt = (int)(t2 >> 5);
        int mloc = mt * 16 + (lane & 15);
        int c0 = kt * 64 + kk * 32 + ((lane >> 4) << 3);
        const float* t1r = T1 + (size_t)mloc * HXc + c0;
        short o8[8];
        #pragma unroll
        for (int i = 0; i < 8; ++i) o8[i] = f2bf(t1r[i]);
        *(bf16x8*)(T1p + grp * 8) = *(bf16x8*)o8;
    } else {
        // ---- act_delta: A1p = bf16(tanh(XW+SW[j]) - T1), slab layout; 4096 act blocks ----
        int act_idx = (b < 64) ? (b - (b >> 3) - 1) : (56 + (b - 272));
        size_t grp = (size_t)act_idx * 512 + tid;    // 2,097,152 groups
        int lane = (int)(grp & 63);
        size_t t2 = grp >> 6;
        int kk = (int)(t2 & 1);
        int mt = (int)((t2 >> 1) & 15);
        int kt = (int)((t2 >> 5) & 15);
        int j  = (int)(t2 >> 9);             // 0..63
        int mloc = mt * 16 + (lane & 15);
        int c0 = kt * 64 + kk * 32 + ((lane >> 4) << 3);
        const float* xwr = XW + (size_t)mloc * HXc + c0;
        const float* t1r = T1 + (size_t)mloc * HXc + c0;
        const float* swr = SW + (size_t)j * HXc + c0;
        short o8[8];
        #pragma unroll
        for (int i = 0; i < 8; ++i)
            o8[i] = f2bf(fast_tanh(xwr[i] + swr[i]) - t1r[i]);
        *(bf16x8*)(A1p + grp * 8) = *(bf16x8*)o8;
    }
}

// ---------------- tbgemm: TB = tanh(T1@W12 + (tk+tau)*Wb1[0] + cY + c0row) ----------------
// 64 blocks of 64x128 tiles (bmT = b&3, bnT = b>>2), 256 threads (4 waves, 1m x 4n), BK=32, S=32.
// Separate dispatch (R13's intra-dispatch fusion regressed +50us: consumer needed ALL w12 blocks).
__global__ __launch_bounds__(256) void tbgemm_kernel(
    const short* __restrict__ T1p, const short* __restrict__ W12p,
    const float* __restrict__ cY, const float* __restrict__ c0row,
    const float* __restrict__ Wb1, const float* __restrict__ times_t,
    const float* __restrict__ times_tau, const int* kptr,
    float* __restrict__ TB){
    __shared__ __align__(16) short As[2][2048];
    __shared__ __align__(16) short Bs[2][4096];
    int tid = threadIdx.x;
    int wave = tid >> 6, lane = tid & 63;
    int wn = wave;
    int bmT = blockIdx.x & 3, bnT = blockIdx.x >> 2;
    int quad = lane >> 4, llo = lane & 15;
    int slabB = bnT >> 1, halfB = bnT & 1;
    const short* Bb = W12p + (size_t)slabB * 16 * 32 * 512;
    f32x4 acc[4][2];
    #pragma unroll
    for (int i = 0; i < 4; ++i)
        #pragma unroll
        for (int j = 0; j < 2; ++j) acc[i][j] = (f32x4){0.f, 0.f, 0.f, 0.f};
#define TBSTAGE(s, buf) {                                                                          \
        int kt_ = (s) >> 1, kk_ = (s) & 1;                                                         \
        _Pragma("unroll") for (int c = 0; c < 3; ++c){                                             \
            int ci = wave * 3 + c;                                                                 \
            if (ci < 4){                                                                           \
                size_t ch = (size_t)kt_ * 32 + ((bmT * 4 + ci) << 1) + kk_;                        \
                gld_lds16(T1p + ch * 512 + lane * 8, As[buf] + ci * 512);                          \
            } else {                                                                               \
                int t = ci - 4;                                                                    \
                size_t ch = (size_t)kt_ * 32 + ((halfB * 8 + t) << 1) + kk_;                       \
                gld_lds16(Bb + ch * 512 + lane * 8, Bs[buf] + t * 512);                            \
            }                                                                                      \
        } }
    TBSTAGE(0, 0);
    for (int s = 0; s < 32; ++s){
        int buf = s & 1;
        __syncthreads();
        if (s + 1 < 32) TBSTAGE(s + 1, buf ^ 1);
        bf16x8 af[4], bfr[2];
        #pragma unroll
        for (int i = 0; i < 4; ++i) af[i] = *(const bf16x8*)(As[buf] + i * 512 + lane * 8);
        #pragma unroll
        for (int j = 0; j < 2; ++j) bfr[j] = *(const bf16x8*)(Bs[buf] + (wn * 2 + j) * 512 + lane * 8);
        #pragma unroll
        for (int i = 0; i < 4; ++i)
            #pragma unroll
            for (int j = 0; j < 2; ++j)
                acc[i][j] = __builtin_amdgcn_mfma_f32_16x16x32_bf16(af[i], bfr[j], acc[i][j], 0, 0, 0);
    }
#undef TBSTAGE
    float tk = times_t[kptr[0]];
    #pragma unroll
    for (int i = 0; i < 4; ++i){
        #pragma unroll
        for (int r = 0; r < 4; ++r){
            int m = bmT * 64 + i * 16 + quad * 4 + r;
            float tv = tk + times_tau[m];
            #pragma unroll
            for (int j = 0; j < 2; ++j){
                int h = bnT * 128 + wn * 32 + j * 16 + llo;
                float z = acc[i][j][r] + tv * Wb1[h] + cY[h] + c0row[h];
                TB[(size_t)m * HBc + h] = fast_tanh(z);
            }
        }
    }
}

// ================== gemm_big: 256x256 tile, BK=64, 8-wave, 8-phase counted-vmcnt (frozen) ==================
// Dz2 = A1p(16384x1024) @ W12p(1024x2048), fused tanh-delta epilogue. grid (64,8), 512 threads.
// LDS 128 KiB (1 block/CU). 88.3-90us, 6x confirmed.
//   ph1:T+1.A0  ph2:T+1.A1  ph3:T+2.B0  ph4:T+2.B1+vmcnt(4)
//   ph5:T+2.A0  ph6:T+2.A1  ph7:T+3.B0  ph8:T+3.B1+vmcnt(4)
__device__ __forceinline__ void stage_half(const short* __restrict__ base, short* lbase,
                                           int wave, int lane){
    const short* s = base + (size_t)(wave * 2) * 512 + lane * 8;
    short* d = lbase + (wave * 2) * 512;
    gld_lds16(s, d);
    gld_lds16(s + 512, d + 512);
}

__global__ __launch_bounds__(512, 2) void gemm_big(
    const short* __restrict__ Ap, const short* __restrict__ Bp,
    const float* __restrict__ TB, const float* __restrict__ wrow,
    float* __restrict__ dacc){
    __shared__ __align__(16) short As[2][16384];
    __shared__ __align__(16) short Bs[2][16384];
    __shared__ float redn[256];
    int tid = threadIdx.x;
    int wave = tid >> 6, lane = tid & 63;
    int wm = wave >> 2, wn = wave & 3;
    int bm = blockIdx.x, bn = blockIdx.y;
    int quad = lane >> 4, llo = lane & 15;
    const short* Ab = Ap + (size_t)bm * 16 * 32 * 512;   // 256-row slab: 16 ktiles x 32 chunks x 1KB
    const short* Bb = Bp + (size_t)bn * 16 * 32 * 512;   // 256-col slab

    f32x4 acc[8][4];
    #pragma unroll
    for (int i = 0; i < 8; ++i)
        #pragma unroll
        for (int j = 0; j < 4; ++j) acc[i][j] = (f32x4){0.f, 0.f, 0.f, 0.f};

    bf16x8 af[4][2];
    bf16x8 bfr[4][2];

#define BARX() __builtin_amdgcn_s_barrier()
#define GATE4() asm volatile("s_waitcnt vmcnt(4)" ::: "memory")
#define GATE0() asm volatile("s_waitcnt vmcnt(0)" ::: "memory")
#define STAGE_A(kt, h, buf) stage_half(Ab + ((size_t)(kt) * 32 + (h) * 16) * 512, &As[buf][(h) * 16 * 512], wave, lane)
#define STAGE_B(kt, h, buf) stage_half(Bb + ((size_t)(kt) * 32 + (h) * 16) * 512, &Bs[buf][(h) * 16 * 512], wave, lane)
#define RD_A(buf, ib) { _Pragma("unroll") for (int i_ = 0; i_ < 4; ++i_)                                   \
        _Pragma("unroll") for (int k_ = 0; k_ < 2; ++k_)                                                   \
            af[i_][k_] = *(const bf16x8*)&As[buf][(((wm * 8 + (ib) + i_) * 2 + k_) * 512) + lane * 8]; }
#define RD_B(buf, jb) { _Pragma("unroll") for (int j_ = 0; j_ < 2; ++j_)                                   \
        _Pragma("unroll") for (int k_ = 0; k_ < 2; ++k_)                                                   \
            bfr[(jb) + j_][k_] = *(const bf16x8*)&Bs[buf][(((wn * 4 + (jb) + j_) * 2 + k_) * 512) + lane * 8]; }
#define MFMA16(mb, nb) { _Pragma("unroll") for (int k_ = 0; k_ < 2; ++k_)                                  \
        _Pragma("unroll") for (int i_ = 0; i_ < 4; ++i_)                                                   \
        _Pragma("unroll") for (int j_ = 0; j_ < 2; ++j_)                                                   \
            acc[(mb) + i_][(nb) + j_] = __builtin_amdgcn_mfma_f32_16x16x32_bf16(                           \
                af[i_][k_], bfr[(nb) + j_][k_], acc[(mb) + i_][(nb) + j_], 0, 0, 0); }
#define PH(reads, stage, mfma, gate) do {                                                                  \
        reads; stage;                                                                                      \
        BARX();                                                                                            \
        __builtin_amdgcn_s_setprio(1); mfma; __builtin_amdgcn_s_setprio(0);                                \
        gate;                                                                                              \
        BARX(); } while (0)

    // prologue: tile0 (B then A) + tile1 B; vmcnt(4) -> tile0 fully resident, 1.B in flight
    STAGE_B(0, 0, 0); STAGE_B(0, 1, 0);
    STAGE_A(0, 0, 0); STAGE_A(0, 1, 0);
    STAGE_B(1, 0, 1); STAGE_B(1, 1, 1);
    GATE4();
    BARX();

    for (int T = 0; T < 14; T += 2){
        PH(RD_A(0, 0); RD_B(0, 0), STAGE_A(T + 1, 0, 1), MFMA16(0, 0), );
        PH(RD_B(0, 2),             STAGE_A(T + 1, 1, 1), MFMA16(0, 2), );
        PH(RD_A(0, 4),             STAGE_B(T + 2, 0, 0), MFMA16(4, 0), );
        PH(                      , STAGE_B(T + 2, 1, 0), MFMA16(4, 2), GATE4());
        PH(RD_A(1, 0); RD_B(1, 0), STAGE_A(T + 2, 0, 0), MFMA16(0, 0), );
        PH(RD_B(1, 2),             STAGE_A(T + 2, 1, 0), MFMA16(0, 2), );
        PH(RD_A(1, 4),             STAGE_B(T + 3, 0, 1), MFMA16(4, 0), );
        PH(                      , STAGE_B(T + 3, 1, 1), MFMA16(4, 2), GATE4());
    }
    // peeled final iteration: T=14 (tiles 14,15); only 15.A0/A1 remain to stage
    PH(RD_A(0, 0); RD_B(0, 0), STAGE_A(15, 0, 1), MFMA16(0, 0), );
    PH(RD_B(0, 2),             STAGE_A(15, 1, 1), MFMA16(0, 2), );
    PH(RD_A(0, 4),           ,                    MFMA16(4, 0), );
    PH(                      , ,                  MFMA16(4, 2), GATE0());
    PH(RD_A(1, 0); RD_B(1, 0), ,                  MFMA16(0, 0), );
    PH(RD_B(1, 2),             ,                  MFMA16(0, 2), );
    PH(RD_A(1, 4),             ,                  MFMA16(4, 0), );
    PH(                      , ,                  MFMA16(4, 2), );

#undef PH
#undef MFMA16
#undef RD_B
#undef RD_A
#undef STAGE_B
#undef STAGE_A
#undef GATE0
#undef GATE4
#undef BARX

    // fused epilogue: tanh(zb+dz)-tanh(zb) = tdz*(1-tb^2)/(1+tb*tdz), weighted by wrow, reduce over m
    int nj[4];
    #pragma unroll
    for (int j = 0; j < 4; ++j) nj[j] = bn * 256 + wn * 64 + j * 16 + llo;
    float part[4] = {};
    #pragma unroll
    for (int i = 0; i < 8; ++i){
        #pragma unroll
        for (int r = 0; r < 4; ++r){
            int m = bm * 256 + wm * 128 + i * 16 + quad * 4 + r;
            float wr = wrow[m];
            const float* trow = TB + (size_t)(m & 255) * HBc;
            #pragma unroll
            for (int j = 0; j < 4; ++j){
                float tb  = trow[nj[j]];
                float tdz = fast_tanh(acc[i][j][r]);
                float num = tdz * (1.0f - tb * tb);
                float den = 1.0f + tb * tdz;
                part[j] += wr * num * __builtin_amdgcn_rcpf(den);
            }
        }
    }
    #pragma unroll
    for (int j = 0; j < 4; ++j){
        part[j] += __shfl_xor(part[j], 16);
        part[j] += __shfl_xor(part[j], 32);
    }
    if (tid < 256) redn[tid] = 0.f;
    __syncthreads();
    if (quad == 0){
        #pragma unroll
        for (int j = 0; j < 4; ++j)
            atomicAdd(&redn[wn * 64 + j * 16 + llo], part[j]);
    }
    __syncthreads();
    if (tid < 256) atomicAdd(&dacc[bn * 256 + tid], redn[tid]);
}

// ---------------- si = dacc @ Wb2, split over 8 blocks (out pre-zeroed in prep) ----------------
__global__ void out_kernel(const float* __restrict__ dacc, const float* __restrict__ Wb2,
                           float* __restrict__ out){
    __shared__ float red[4][64];
    int tid = threadIdx.x;
    int g = tid & 63, seg = tid >> 6;
    int h0 = blockIdx.x * 256 + seg * 64;
    float s = 0.f;
    #pragma unroll 8
    for (int hh = 0; hh < 64; ++hh)
        s += dacc[h0 + hh] * Wb2[(size_t)(h0 + hh) * GOUTc + g];
    red[seg][g] = s;
    __syncthreads();
    if (tid < 64)
        atomicAdd(&out[tid], red[0][tid] + red[1][tid] + red[2][tid] + red[3][tid]);
}

extern "C" void kernel_launch(void* const* d_in, const int* in_sizes, int n_in,
                              void* d_out, int out_size, void* d_ws, size_t ws_size,
                              hipStream_t stream){
    const float* X         = (const float*)d_in[0];
    const float* Y         = (const float*)d_in[1];
    const float* R         = (const float*)d_in[2];
    const float* stoich    = (const float*)d_in[3];
    const float* times_t   = (const float*)d_in[4];
    const float* times_tau = (const float*)d_in[5];
    const float* Wx1 = (const float*)d_in[6];
    const float* bx1 = (const float*)d_in[7];
    const float* Wx2 = (const float*)d_in[8];
    const float* bx2 = (const float*)d_in[9];
    const float* Wih = (const float*)d_in[10];
    const float* Whh = (const float*)d_in[11];
    const float* bh  = (const float*)d_in[12];
    const float* Wb1 = (const float*)d_in[13];
    const float* bb1 = (const float*)d_in[14];
    const float* Wb2 = (const float*)d_in[15];
    // d_in[16] = bb2: cancels in (nn_disp - nn), unused
    const int* kp  = (const int*)d_in[17];
    const int* kpp = (const int*)d_in[18];
    const int* qp  = (const int*)d_in[19];
    const int* qpp = (const int*)d_in[20];
    float* out = (float*)d_out;

    float* ws     = (float*)d_ws;
    float* hb0    = ws;                        // 512
    float* hb1    = ws + 512;                  // 512
    float* cY     = ws + 1024;                 // 2048
    float* dacc   = ws + 3072;                 // 2048
    float* wrow   = ws + 5120;                 // 64*256 = 16384
    float* SW     = ws + 21504;                // 64*1024 = 65536
    float* XW     = ws + 87040;                // 256*1024 = 262144
    float* T1     = ws + 349184;               // 256*1024 = 262144
    float* c0row  = ws + 611328;               // 2048
    float* TB     = ws + 742400;               // 256*2048 = 524288
    short* T1p    = (short*)(ws + 1266688);    // 256*1024 bf16 = 131,072 float slots
    short* A1p    = (short*)(ws + 1790976);    // 16384*1024 bf16 = 8,388,608 float slots
    short* Wx2a   = (short*)(ws + 10179584);   // 1024*512 bf16 = 262,144 float slots
    short* Wb1p   = (short*)(ws + 10441728);   // 512*2048 bf16 = 524,288 float slots
    short* W12p   = (short*)(ws + 10966016);   // 1024*2048 bf16 = 1,048,576 float slots
    int*   cnt    = (int*)(ws + 12014592);     // 4 ints: rnn-step, (unused), (unused), (unused)

    prep_kernel  <<<2177, 256, 0, stream>>>(stoich, Wx1, Wx2, Wb1, X, R, bx1, bx2, bb1, kpp, qpp,
                                            SW, Wx2a, Wb1p, XW, T1, wrow, hb0, dacc, out,
                                            c0row, cY, cnt);
    mid_kernel   <<<4312, 512, 0, stream>>>(XW, T1, SW, A1p, T1p, Y, Wih, Whh, bh, Wb1,
                                            kp, qp, hb0, hb1, cnt, cY, Wx2a, Wb1p, W12p);
    tbgemm_kernel<<<64,   256, 0, stream>>>(T1p, W12p, cY, c0row, Wb1, times_t, times_tau, kp, TB);
    gemm_big     <<<dim3(64, 8), 512, 0, stream>>>(A1p, W12p, TB, wrow, dacc);
    out_kernel   <<<8,    256, 0, stream>>>(dacc, Wb2, out);
}

// Round 15
// 252.586 us; speedup vs baseline: 1.2013x; 1.0943x over previous
//
#include <hip/hip_runtime.h>
#include <math.h>

// Shapes (fixed by the reference)
#define DXc   16
#define MRc   64
#define MBARc 256
#define NTc   9
#define DYc   8
#define HXc   1024
#define EXc   512
#define HRc   512
#define HBc   2048
#define GOUTc 64
#define TOTc  2049   // (NT-1)*MBAR + 1

using bf16x8 = __attribute__((ext_vector_type(8))) short;
using f32x4  = __attribute__((ext_vector_type(4))) float;

typedef unsigned int u32;
typedef u32 __attribute__((address_space(1))) gbl_u32;
typedef u32 __attribute__((address_space(3))) lds_u32;

__device__ __forceinline__ float fast_tanh(float x){
    float e = __expf(2.0f * x);
    return 1.0f - 2.0f / (e + 1.0f);
}

// fp32 -> bf16 round-to-nearest-even (bit pattern in a short)
__device__ __forceinline__ short f2bf(float f){
    unsigned u = __builtin_bit_cast(unsigned, f);
    u = (u + 0x7FFFu + ((u >> 16) & 1u)) >> 16;
    return (short)u;
}

// async global->LDS: each lane loads 16 B from g + lane*16; LDS dest = base + lane*16
__device__ __forceinline__ void gld_lds16(const short* g, short* l){
    __builtin_amdgcn_global_load_lds((const gbl_u32*)g, (lds_u32*)l, 16, 0, 0);
}

// ---------------- prep: SW + packs + XW/T1 + wrow + c0row(64-block parallel) + inits ----------------
// grid 2177 x 256
__global__ void prep_kernel(const float* __restrict__ stoich, const float* __restrict__ Wx1,
                            const float* __restrict__ Wx2, const float* __restrict__ Wb1,
                            const float* __restrict__ X, const float* __restrict__ R,
                            const float* __restrict__ bx1, const float* __restrict__ bx2,
                            const float* __restrict__ bb1,
                            const int* kpptr, const int* qpptr,
                            float* __restrict__ SW, short* __restrict__ Wx2a,
                            short* __restrict__ Wb1p, float* __restrict__ XW,
                            float* __restrict__ T1, float* __restrict__ wrow,
                            float* __restrict__ hb0, float* __restrict__ dacc,
                            float* __restrict__ outz, float* __restrict__ c0row,
                            float* __restrict__ cY, int* __restrict__ cnt){
    int b = blockIdx.x, tid = threadIdx.x;
    if (b < 256){
        // SW[j][c] = stoich[:,j] @ Wx1
        int idx = b * 256 + tid;
        int j = idx >> 10, c = idx & 1023;
        float acc = 0.f;
        #pragma unroll
        for (int d = 0; d < DXc; ++d) acc += stoich[d * MRc + j] * Wx1[d * HXc + c];
        SW[idx] = acc;
    } else if (b < 512){
        // pack Wx2 (1024x512) into MFMA A-fragment order (M=c rows, K=e), KTOT=16, layout [chunk][kt][512]
        size_t grp = (size_t)(b - 256) * 256 + tid;    // 65536 groups
        int lane = grp & 63;
        size_t t2 = grp >> 6;
        int kt = t2 & 15, mt = t2 >> 4;                // mt 0..63
        int c  = mt * 16 + (lane & 15);
        int e0 = kt * 32 + ((lane >> 4) << 3);
        short o8[8];
        #pragma unroll
        for (int jj = 0; jj < 8; ++jj) o8[jj] = f2bf(Wx2[(size_t)c * EXc + e0 + jj]);
        *(bf16x8*)(Wx2a + grp * 8) = *(bf16x8*)o8;
    } else if (b < 1024){
        // pack Wb1 rows 1..512 (512x2048) into B-fragment order, KTOT=16, layout [chunk][kt][512]
        size_t grp = (size_t)(b - 512) * 256 + tid;
        int lane = grp & 63;
        size_t t2 = grp >> 6;
        int kt = t2 & 15, nt = t2 >> 4;
        int n  = nt * 16 + (lane & 15);
        int k0 = kt * 32 + ((lane >> 4) << 3);
        short o8[8];
        #pragma unroll
        for (int jj = 0; jj < 8; ++jj) o8[jj] = f2bf(Wb1[(size_t)(1 + k0 + jj) * HBc + n]);
        *(bf16x8*)(Wb1p + grp * 8) = *(bf16x8*)o8;
    } else if (b < 2048){
        // XW = Xbase@Wx1 + bx1 ; T1 = tanh(XW)
        int idx = (b - 1024) * 256 + tid;
        int m = idx >> 10, c = idx & 1023;
        int base = kpptr[0] * MBARc;
        const float* xr = X + ((size_t)qpptr[0] * TOTc + base + m) * DXc;
        float acc = bx1[c];
        #pragma unroll
        for (int d = 0; d < DXc; ++d) acc += xr[d] * Wx1[d * HXc + c];
        XW[idx] = acc;
        T1[idx] = fast_tanh(acc);
    } else if (b < 2112){
        // wrow[j*256+m] = valid(j,m) * R_delta
        int j = b - 2048, m = tid;
        int base = kpptr[0] * MBARc;
        int qp = qpptr[0];
        const float* xr = X + ((size_t)qp * TOTc + base + m) * DXc;
        bool valid = true;
        #pragma unroll
        for (int d = 0; d < DXc; ++d) valid = valid && (xr[d] + stoich[d * MRc + j] >= 0.f);
        size_t rb = (size_t)qp * TOTc * MRc;
        float rd = R[rb + (size_t)(base + 1 + m) * MRc + j] - R[rb + (size_t)(base + m) * MRc + j];
        wrow[j * MBARc + m] = valid ? rd : 0.f;
    } else if (b == 2112){
        hb0[tid] = 0.f; hb0[tid + 256] = 0.f;
        #pragma unroll
        for (int l = 0; l < 8; ++l) dacc[tid + l * 256] = 0.f;
        #pragma unroll
        for (int l = 0; l < 8; ++l) cY[tid + l * 256] = bb1[tid + l * 256];
        if (tid < GOUTc) outz[tid] = 0.f;
        if (tid == 0){ cnt[0] = 0; cnt[1] = 0; cnt[2] = 0; cnt[3] = 0; }
    } else {
        // c0row[h] = bx2 @ Wb1[1:513, h]; 64 blocks x 32 h, 8 e-segments reduced in LDS
        __shared__ float cps[32][8];
        int bb = b - 2113;                  // 0..63
        int hl = tid & 31, sg = tid >> 5;   // 32 h x 8 segs
        int h = bb * 32 + hl, e0 = sg * 64;
        float a = 0.f;
        #pragma unroll 8
        for (int e = 0; e < 64; ++e)
            a += bx2[e0 + e] * Wb1[(size_t)(1 + e0 + e) * HBc + h];
        cps[hl][sg] = a;
        __syncthreads();
        if (sg == 0){
            float s = 0.f;
            #pragma unroll
            for (int r = 0; r < 8; ++r) s += cps[hl][r];
            c0row[h] = s;
        }
    }
}

// ---- MFMA helpers (4x4 grid, used by w12) ----
#define MMGRID(aa, bb) {                                                       \
    _Pragma("unroll") for (int i_ = 0; i_ < 4; ++i_)                           \
        _Pragma("unroll") for (int j_ = 0; j_ < 4; ++j_)                       \
            acc[i_][j_] = __builtin_amdgcn_mfma_f32_16x16x32_bf16(aa[i_], bb[j_], acc[i_][j_], 0, 0, 0); }

// stage BK=32 (1 kt) from [chunk][kt][512] layout: 8 A + 8 B chunks of 1 KB; waves 0..3 stage 4 each
__device__ __forceinline__ void stage32(const short* __restrict__ Ap, const short* __restrict__ Bp,
                                        short* As, short* Bs,
                                        int at0, int bt0, int s, int KTOT, int wave, int lane){
    #pragma unroll
    for (int c = 0; c < 4; ++c){
        int ci = wave * 4 + c;            // 0..15
        int half = ci >> 3;               // 0 = A, 1 = B
        int t    = ci & 7;
        const short* src = half ? (Bp + ((size_t)(bt0 + t) * KTOT + s) * 512 + lane * 8)
                                : (Ap + ((size_t)(at0 + t) * KTOT + s) * 512 + lane * 8);
        short* dst = (half ? Bs : As) + t * 512;
        gld_lds16(src, dst);
    }
}

#define STAGE_COMPUTE(As, Bs) {                                                       \
    bf16x8 af[4], bfr[4];                                                             \
    _Pragma("unroll") for (int i_ = 0; i_ < 4; ++i_)                                  \
        af[i_] = *(const bf16x8*)((As) + ((wm * 4 + i_) * 512) + lane * 8);           \
    _Pragma("unroll") for (int j_ = 0; j_ < 4; ++j_)                                  \
        bfr[j_] = *(const bf16x8*)((Bs) + ((wn * 4 + j_) * 512) + lane * 8);          \
    MMGRID(af, bfr); }

// ================ mid: RNN(reg-Whh) + cY + w12 + T1p + act_delta, ONE dispatch ================
// blocks [0,8):      RNN, Whh slice held in 64 VGPR/thread (no big LDS -> no occupancy poisoning)
// blocks [8,24):     cY (sleep-spin on cnt==64)
// blocks [24,152):   w12 gemm, double-buffered 32KB (waves 0..3 active)
// blocks [152,216):  T1p pack (512-thread)
// blocks [216,4312): act_delta (512-thread)
// Union LDS = 32 KB -> act blocks run 4 blocks/CU; the ~30us serial RNN chain hides under act.
// R10/R12 measured: non-gemm total dropped ~180 -> ~165us with this structure. R13 (tbgemm chained
// in-dispatch, +50us) and R14 (XCD-colocated RNN ids, +23us) both regressed — keep THIS layout.
__global__ __launch_bounds__(512) void mid_kernel(
    const float* __restrict__ XW, const float* __restrict__ T1,
    const float* __restrict__ SW, short* __restrict__ A1p, short* __restrict__ T1p,
    const float* __restrict__ Y, const float* __restrict__ Wih,
    const float* __restrict__ Whh, const float* __restrict__ bh,
    const float* __restrict__ Wb1,
    const int* kptr, const int* qptr,
    float* __restrict__ hb0, float* __restrict__ hb1,
    int* __restrict__ cnt, float* __restrict__ cY,
    const short* __restrict__ Wx2a, const short* __restrict__ Wb1p,
    short* __restrict__ W12p){
    __shared__ __align__(16) char smem[32768];   // union: rnn 4K | cY 0.5K | w12 32K
    int b = blockIdx.x, tid = threadIdx.x;
    if (b < 8){
        // ---- RNN: Whh[:, out] segment in registers; 8 blocks co-resident, cnt-gated ----
        float* hs = (float*)smem;                              // 512
        float (*psum)[64] = (float(*)[64])(smem + 2048);       // [8][64]
        int o = tid & 63, seg = tid >> 6;
        int out = b * 64 + o;
        int k = kptr[0], q = qptr[0];
        float wreg[64];
        #pragma unroll
        for (int l = 0; l < 64; ++l)
            wreg[l] = Whh[(size_t)(seg * 64 + l) * HRc + out];
        hs[tid] = 0.f;
        __syncthreads();
        for (int s = 0; s < 8; ++s){
            float* dst = (s & 1) ? hb0 : hb1;
            if (s > 0){
                const float* src = (s & 1) ? hb1 : hb0;
                if (tid == 0){
                    int guard = 0;
                    while (__hip_atomic_load(cnt, __ATOMIC_ACQUIRE, __HIP_MEMORY_SCOPE_AGENT) < 8 * s
                           && ++guard < (1 << 26)) {}
                }
                __syncthreads();
                hs[tid] = __hip_atomic_load(src + tid, __ATOMIC_RELAXED, __HIP_MEMORY_SCOPE_AGENT);
                __syncthreads();
            }
            int t = k + 1 + s;
            if (t < NTc){
                int k0 = seg * 64;
                float a0 = 0.f, a1 = 0.f, a2 = 0.f, a3 = 0.f;
                #pragma unroll
                for (int kk = 0; kk < 64; kk += 4){
                    a0 += hs[k0 + kk + 0] * wreg[kk + 0];
                    a1 += hs[k0 + kk + 1] * wreg[kk + 1];
                    a2 += hs[k0 + kk + 2] * wreg[kk + 2];
                    a3 += hs[k0 + kk + 3] * wreg[kk + 3];
                }
                psum[seg][o] = (a0 + a1) + (a2 + a3);
                __syncthreads();
                if (seg == 0){
                    float a = 0.f;
                    #pragma unroll
                    for (int r = 0; r < 8; ++r) a += psum[r][o];
                    const float* y = Y + (q * NTc + t) * DYc;
                    float z = bh[out];
                    #pragma unroll
                    for (int d = 0; d < DYc; ++d) z += y[d] * Wih[d * HRc + out];
                    __hip_atomic_store(dst + out, fast_tanh(z + a), __ATOMIC_RELEASE, __HIP_MEMORY_SCOPE_AGENT);
                }
                __syncthreads();
            } else {
                if (seg == 0)
                    __hip_atomic_store(dst + out, hs[out], __ATOMIC_RELEASE, __HIP_MEMORY_SCOPE_AGENT);
                __syncthreads();
            }
            if (tid == 0)
                __hip_atomic_fetch_add(cnt, 1, __ATOMIC_RELEASE, __HIP_MEMORY_SCOPE_AGENT);
        }
    } else if (b < 24){
        // ---- cY: 16 blocks = 4 e-chunks x 4 h-chunks; SLEEP-spin until RNN done (cnt==64) ----
        float* hs2 = (float*)smem;   // 128 floats
        int bb = b - 8;
        int e0 = (bb >> 2) * 128, h = (bb & 3) * 512 + tid;
        if (tid == 0){
            int guard = 0;
            while (__hip_atomic_load(cnt, __ATOMIC_ACQUIRE, __HIP_MEMORY_SCOPE_AGENT) < 64
                   && ++guard < (1 << 20)) {
                __builtin_amdgcn_s_sleep(32);
            }
        }
        __syncthreads();
        if (tid < 128)
            hs2[tid] = __hip_atomic_load(hb0 + e0 + tid, __ATOMIC_RELAXED, __HIP_MEMORY_SCOPE_AGENT);
        __syncthreads();
        float acc = 0.f;
        #pragma unroll 4
        for (int e = 0; e < 128; ++e)
            acc += hs2[e] * Wb1[(size_t)(1 + EXc + e0 + e) * HBc + h];
        atomicAdd(&cY[h], acc);
    } else if (b < 152){
        // ---- w12: 128 blocks, 128x128 tiles, K=512 (S=16), double-buffered; waves 0..3 active ----
        short (*Asb)[4096] = (short(*)[4096])smem;
        short (*Bsb)[4096] = (short(*)[4096])(smem + 16384);
        const int KTOT = 16, S = 16;
        int bw = b - 24;
        int wave = tid >> 6, lane = tid & 63;
        bool active = wave < 4;
        int wm = wave >> 1, wn = wave & 1;
        int bx = bw & 15, by = bw >> 4;
        int quad = lane >> 4, llo = lane & 15;
        f32x4 acc[4][4];
        #pragma unroll
        for (int i = 0; i < 4; ++i)
            #pragma unroll
            for (int j = 0; j < 4; ++j) acc[i][j] = (f32x4){0.f, 0.f, 0.f, 0.f};
        if (active) stage32(Wx2a, Wb1p, Asb[0], Bsb[0], by * 8, bx * 8, 0, KTOT, wave, lane);
        for (int s = 0; s < S; ++s){
            int buf = s & 1;
            __syncthreads();
            if (active && s + 1 < S)
                stage32(Wx2a, Wb1p, Asb[buf ^ 1], Bsb[buf ^ 1], by * 8, bx * 8, s + 1, KTOT, wave, lane);
            if (active) STAGE_COMPUTE(Asb[buf], Bsb[buf]);
        }
        if (active){
            // write W12[c][h] into gemm slab layout: [slab=h>>8][kt=c>>6][chunk=((h>>4)&15)*2+((c>>5)&1)]
            #pragma unroll
            for (int j = 0; j < 4; ++j){
                int h = bx * 128 + wn * 64 + j * 16 + llo;
                #pragma unroll
                for (int i = 0; i < 4; ++i){
                    #pragma unroll
                    for (int r = 0; r < 4; ++r){
                        int c = by * 128 + wm * 64 + i * 16 + quad * 4 + r;
                        size_t idx = ((((size_t)(h >> 8) * 16 + (c >> 6)) * 32)
                                      + ((h >> 4) & 15) * 2 + ((c >> 5) & 1)) * 512
                                   + (size_t)(((c >> 3) & 3) * 16 + (h & 15)) * 8 + (c & 7);
                        W12p[idx] = f2bf(acc[i][j][r]);
                    }
                }
            }
        }
    } else if (b < 216){
        // ---- T1p: pack T1 (256x1024) into slab layout (64 blocks x 512 threads) ----
        size_t grp = (size_t)(b - 152) * 512 + tid;   // 32768 groups
        int lane = (int)(grp & 63);
        size_t t2 = grp >> 6;                         // kt*32 + mt*2 + kk
        int kk = (int)(t2 & 1);
        int mt = (int)((t2 >> 1) & 15);
        int kt = (int)(t2 >> 5);
        int mloc = mt * 16 + (lane & 15);
        int c0 = kt * 64 + kk * 32 + ((lane >> 4) << 3);
        const float* t1r = T1 + (size_t)mloc * HXc + c0;
        short o8[8];
        #pragma unroll
        for (int i = 0; i < 8; ++i) o8[i] = f2bf(t1r[i]);
        *(bf16x8*)(T1p + grp * 8) = *(bf16x8*)o8;
    } else {
        // ---- act_delta: A1p = bf16(tanh(XW+SW[j]) - T1), slab layout (4096 blocks x 512 threads) ----
        size_t grp = (size_t)(b - 216) * 512 + tid;  // 2,097,152 groups
        int lane = (int)(grp & 63);
        size_t t2 = grp >> 6;
        int kk = (int)(t2 & 1);
        int mt = (int)((t2 >> 1) & 15);
        int kt = (int)((t2 >> 5) & 15);
        int j  = (int)(t2 >> 9);             // 0..63
        int mloc = mt * 16 + (lane & 15);
        int c0 = kt * 64 + kk * 32 + ((lane >> 4) << 3);
        const float* xwr = XW + (size_t)mloc * HXc + c0;
        const float* t1r = T1 + (size_t)mloc * HXc + c0;
        const float* swr = SW + (size_t)j * HXc + c0;
        short o8[8];
        #pragma unroll
        for (int i = 0; i < 8; ++i)
            o8[i] = f2bf(fast_tanh(xwr[i] + swr[i]) - t1r[i]);
        *(bf16x8*)(A1p + grp * 8) = *(bf16x8*)o8;
    }
}

// ---------------- tbgemm: TB = tanh(T1@W12 + (tk+tau)*Wb1[0] + cY + c0row) ----------------
// 64 blocks of 64x128 tiles (bmT = b&3, bnT = b>>2), 256 threads (4 waves, 1m x 4n), BK=32, S=32.
__global__ __launch_bounds__(256) void tbgemm_kernel(
    const short* __restrict__ T1p, const short* __restrict__ W12p,
    const float* __restrict__ cY, const float* __restrict__ c0row,
    const float* __restrict__ Wb1, const float* __restrict__ times_t,
    const float* __restrict__ times_tau, const int* kptr,
    float* __restrict__ TB){
    __shared__ __align__(16) short As[2][2048];
    __shared__ __align__(16) short Bs[2][4096];
    int tid = threadIdx.x;
    int wave = tid >> 6, lane = tid & 63;
    int wn = wave;
    int bmT = blockIdx.x & 3, bnT = blockIdx.x >> 2;
    int quad = lane >> 4, llo = lane & 15;
    int slabB = bnT >> 1, halfB = bnT & 1;
    const short* Bb = W12p + (size_t)slabB * 16 * 32 * 512;
    f32x4 acc[4][2];
    #pragma unroll
    for (int i = 0; i < 4; ++i)
        #pragma unroll
        for (int j = 0; j < 2; ++j) acc[i][j] = (f32x4){0.f, 0.f, 0.f, 0.f};
#define TBSTAGE(s, buf) {                                                                          \
        int kt_ = (s) >> 1, kk_ = (s) & 1;                                                         \
        _Pragma("unroll") for (int c = 0; c < 3; ++c){                                             \
            int ci = wave * 3 + c;                                                                 \
            if (ci < 4){                                                                           \
                size_t ch = (size_t)kt_ * 32 + ((bmT * 4 + ci) << 1) + kk_;                        \
                gld_lds16(T1p + ch * 512 + lane * 8, As[buf] + ci * 512);                          \
            } else {                                                                               \
                int t = ci - 4;                                                                    \
                size_t ch = (size_t)kt_ * 32 + ((halfB * 8 + t) << 1) + kk_;                       \
                gld_lds16(Bb + ch * 512 + lane * 8, Bs[buf] + t * 512);                            \
            }                                                                                      \
        } }
    TBSTAGE(0, 0);
    for (int s = 0; s < 32; ++s){
        int buf = s & 1;
        __syncthreads();
        if (s + 1 < 32) TBSTAGE(s + 1, buf ^ 1);
        bf16x8 af[4], bfr[2];
        #pragma unroll
        for (int i = 0; i < 4; ++i) af[i] = *(const bf16x8*)(As[buf] + i * 512 + lane * 8);
        #pragma unroll
        for (int j = 0; j < 2; ++j) bfr[j] = *(const bf16x8*)(Bs[buf] + (wn * 2 + j) * 512 + lane * 8);
        #pragma unroll
        for (int i = 0; i < 4; ++i)
            #pragma unroll
            for (int j = 0; j < 2; ++j)
                acc[i][j] = __builtin_amdgcn_mfma_f32_16x16x32_bf16(af[i], bfr[j], acc[i][j], 0, 0, 0);
    }
#undef TBSTAGE
    float tk = times_t[kptr[0]];
    #pragma unroll
    for (int i = 0; i < 4; ++i){
        #pragma unroll
        for (int r = 0; r < 4; ++r){
            int m = bmT * 64 + i * 16 + quad * 4 + r;
            float tv = tk + times_tau[m];
            #pragma unroll
            for (int j = 0; j < 2; ++j){
                int h = bnT * 128 + wn * 32 + j * 16 + llo;
                float z = acc[i][j][r] + tv * Wb1[h] + cY[h] + c0row[h];
                TB[(size_t)m * HBc + h] = fast_tanh(z);
            }
        }
    }
}

// ================== gemm_big: 256x256 tile, BK=64, 8-wave, 8-phase counted-vmcnt (frozen) ==================
// Dz2 = A1p(16384x1024) @ W12p(1024x2048), fused tanh-delta epilogue. grid (64,8), 512 threads.
// LDS 128 KiB (1 block/CU). 88.3-90.4us, 7x confirmed; delivery-bound at ~5.8 TB/s staging.
//   ph1:T+1.A0  ph2:T+1.A1  ph3:T+2.B0  ph4:T+2.B1+vmcnt(4)
//   ph5:T+2.A0  ph6:T+2.A1  ph7:T+3.B0  ph8:T+3.B1+vmcnt(4)
__device__ __forceinline__ void stage_half(const short* __restrict__ base, short* lbase,
                                           int wave, int lane){
    const short* s = base + (size_t)(wave * 2) * 512 + lane * 8;
    short* d = lbase + (wave * 2) * 512;
    gld_lds16(s, d);
    gld_lds16(s + 512, d + 512);
}

__global__ __launch_bounds__(512, 2) void gemm_big(
    const short* __restrict__ Ap, const short* __restrict__ Bp,
    const float* __restrict__ TB, const float* __restrict__ wrow,
    float* __restrict__ dacc){
    __shared__ __align__(16) short As[2][16384];
    __shared__ __align__(16) short Bs[2][16384];
    __shared__ float redn[256];
    int tid = threadIdx.x;
    int wave = tid >> 6, lane = tid & 63;
    int wm = wave >> 2, wn = wave & 3;
    int bm = blockIdx.x, bn = blockIdx.y;
    int quad = lane >> 4, llo = lane & 15;
    const short* Ab = Ap + (size_t)bm * 16 * 32 * 512;   // 256-row slab: 16 ktiles x 32 chunks x 1KB
    const short* Bb = Bp + (size_t)bn * 16 * 32 * 512;   // 256-col slab

    f32x4 acc[8][4];
    #pragma unroll
    for (int i = 0; i < 8; ++i)
        #pragma unroll
        for (int j = 0; j < 4; ++j) acc[i][j] = (f32x4){0.f, 0.f, 0.f, 0.f};

    bf16x8 af[4][2];
    bf16x8 bfr[4][2];

#define BARX() __builtin_amdgcn_s_barrier()
#define GATE4() asm volatile("s_waitcnt vmcnt(4)" ::: "memory")
#define GATE0() asm volatile("s_waitcnt vmcnt(0)" ::: "memory")
#define STAGE_A(kt, h, buf) stage_half(Ab + ((size_t)(kt) * 32 + (h) * 16) * 512, &As[buf][(h) * 16 * 512], wave, lane)
#define STAGE_B(kt, h, buf) stage_half(Bb + ((size_t)(kt) * 32 + (h) * 16) * 512, &Bs[buf][(h) * 16 * 512], wave, lane)
#define RD_A(buf, ib) { _Pragma("unroll") for (int i_ = 0; i_ < 4; ++i_)                                   \
        _Pragma("unroll") for (int k_ = 0; k_ < 2; ++k_)                                                   \
            af[i_][k_] = *(const bf16x8*)&As[buf][(((wm * 8 + (ib) + i_) * 2 + k_) * 512) + lane * 8]; }
#define RD_B(buf, jb) { _Pragma("unroll") for (int j_ = 0; j_ < 2; ++j_)                                   \
        _Pragma("unroll") for (int k_ = 0; k_ < 2; ++k_)                                                   \
            bfr[(jb) + j_][k_] = *(const bf16x8*)&Bs[buf][(((wn * 4 + (jb) + j_) * 2 + k_) * 512) + lane * 8]; }
#define MFMA16(mb, nb) { _Pragma("unroll") for (int k_ = 0; k_ < 2; ++k_)                                  \
        _Pragma("unroll") for (int i_ = 0; i_ < 4; ++i_)                                                   \
        _Pragma("unroll") for (int j_ = 0; j_ < 2; ++j_)                                                   \
            acc[(mb) + i_][(nb) + j_] = __builtin_amdgcn_mfma_f32_16x16x32_bf16(                           \
                af[i_][k_], bfr[(nb) + j_][k_], acc[(mb) + i_][(nb) + j_], 0, 0, 0); }
#define PH(reads, stage, mfma, gate) do {                                                                  \
        reads; stage;                                                                                      \
        BARX();                                                                                            \
        __builtin_amdgcn_s_setprio(1); mfma; __builtin_amdgcn_s_setprio(0);                                \
        gate;                                                                                              \
        BARX(); } while (0)

    // prologue: tile0 (B then A) + tile1 B; vmcnt(4) -> tile0 fully resident, 1.B in flight
    STAGE_B(0, 0, 0); STAGE_B(0, 1, 0);
    STAGE_A(0, 0, 0); STAGE_A(0, 1, 0);
    STAGE_B(1, 0, 1); STAGE_B(1, 1, 1);
    GATE4();
    BARX();

    for (int T = 0; T < 14; T += 2){
        PH(RD_A(0, 0); RD_B(0, 0), STAGE_A(T + 1, 0, 1), MFMA16(0, 0), );
        PH(RD_B(0, 2),             STAGE_A(T + 1, 1, 1), MFMA16(0, 2), );
        PH(RD_A(0, 4),             STAGE_B(T + 2, 0, 0), MFMA16(4, 0), );
        PH(                      , STAGE_B(T + 2, 1, 0), MFMA16(4, 2), GATE4());
        PH(RD_A(1, 0); RD_B(1, 0), STAGE_A(T + 2, 0, 0), MFMA16(0, 0), );
        PH(RD_B(1, 2),             STAGE_A(T + 2, 1, 0), MFMA16(0, 2), );
        PH(RD_A(1, 4),             STAGE_B(T + 3, 0, 1), MFMA16(4, 0), );
        PH(                      , STAGE_B(T + 3, 1, 1), MFMA16(4, 2), GATE4());
    }
    // peeled final iteration: T=14 (tiles 14,15); only 15.A0/A1 remain to stage
    PH(RD_A(0, 0); RD_B(0, 0), STAGE_A(15, 0, 1), MFMA16(0, 0), );
    PH(RD_B(0, 2),             STAGE_A(15, 1, 1), MFMA16(0, 2), );
    PH(RD_A(0, 4),           ,                    MFMA16(4, 0), );
    PH(                      , ,                  MFMA16(4, 2), GATE0());
    PH(RD_A(1, 0); RD_B(1, 0), ,                  MFMA16(0, 0), );
    PH(RD_B(1, 2),             ,                  MFMA16(0, 2), );
    PH(RD_A(1, 4),             ,                  MFMA16(4, 0), );
    PH(                      , ,                  MFMA16(4, 2), );

#undef PH
#undef MFMA16
#undef RD_B
#undef RD_A
#undef STAGE_B
#undef STAGE_A
#undef GATE0
#undef GATE4
#undef BARX

    // fused epilogue: tanh(zb+dz)-tanh(zb) = tdz*(1-tb^2)/(1+tb*tdz), weighted by wrow, reduce over m
    int nj[4];
    #pragma unroll
    for (int j = 0; j < 4; ++j) nj[j] = bn * 256 + wn * 64 + j * 16 + llo;
    float part[4] = {};
    #pragma unroll
    for (int i = 0; i < 8; ++i){
        #pragma unroll
        for (int r = 0; r < 4; ++r){
            int m = bm * 256 + wm * 128 + i * 16 + quad * 4 + r;
            float wr = wrow[m];
            const float* trow = TB + (size_t)(m & 255) * HBc;
            #pragma unroll
            for (int j = 0; j < 4; ++j){
                float tb  = trow[nj[j]];
                float tdz = fast_tanh(acc[i][j][r]);
                float num = tdz * (1.0f - tb * tb);
                float den = 1.0f + tb * tdz;
                part[j] += wr * num * __builtin_amdgcn_rcpf(den);
            }
        }
    }
    #pragma unroll
    for (int j = 0; j < 4; ++j){
        part[j] += __shfl_xor(part[j], 16);
        part[j] += __shfl_xor(part[j], 32);
    }
    if (tid < 256) redn[tid] = 0.f;
    __syncthreads();
    if (quad == 0){
        #pragma unroll
        for (int j = 0; j < 4; ++j)
            atomicAdd(&redn[wn * 64 + j * 16 + llo], part[j]);
    }
    __syncthreads();
    if (tid < 256) atomicAdd(&dacc[bn * 256 + tid], redn[tid]);
}

// ---------------- si = dacc @ Wb2, split over 8 blocks (out pre-zeroed in prep) ----------------
__global__ void out_kernel(const float* __restrict__ dacc, const float* __restrict__ Wb2,
                           float* __restrict__ out){
    __shared__ float red[4][64];
    int tid = threadIdx.x;
    int g = tid & 63, seg = tid >> 6;
    int h0 = blockIdx.x * 256 + seg * 64;
    float s = 0.f;
    #pragma unroll 8
    for (int hh = 0; hh < 64; ++hh)
        s += dacc[h0 + hh] * Wb2[(size_t)(h0 + hh) * GOUTc + g];
    red[seg][g] = s;
    __syncthreads();
    if (tid < 64)
        atomicAdd(&out[tid], red[0][tid] + red[1][tid] + red[2][tid] + red[3][tid]);
}

extern "C" void kernel_launch(void* const* d_in, const int* in_sizes, int n_in,
                              void* d_out, int out_size, void* d_ws, size_t ws_size,
                              hipStream_t stream){
    const float* X         = (const float*)d_in[0];
    const float* Y         = (const float*)d_in[1];
    const float* R         = (const float*)d_in[2];
    const float* stoich    = (const float*)d_in[3];
    const float* times_t   = (const float*)d_in[4];
    const float* times_tau = (const float*)d_in[5];
    const float* Wx1 = (const float*)d_in[6];
    const float* bx1 = (const float*)d_in[7];
    const float* Wx2 = (const float*)d_in[8];
    const float* bx2 = (const float*)d_in[9];
    const float* Wih = (const float*)d_in[10];
    const float* Whh = (const float*)d_in[11];
    const float* bh  = (const float*)d_in[12];
    const float* Wb1 = (const float*)d_in[13];
    const float* bb1 = (const float*)d_in[14];
    const float* Wb2 = (const float*)d_in[15];
    // d_in[16] = bb2: cancels in (nn_disp - nn), unused
    const int* kp  = (const int*)d_in[17];
    const int* kpp = (const int*)d_in[18];
    const int* qp  = (const int*)d_in[19];
    const int* qpp = (const int*)d_in[20];
    float* out = (float*)d_out;

    float* ws     = (float*)d_ws;
    float* hb0    = ws;                        // 512
    float* hb1    = ws + 512;                  // 512
    float* cY     = ws + 1024;                 // 2048
    float* dacc   = ws + 3072;                 // 2048
    float* wrow   = ws + 5120;                 // 64*256 = 16384
    float* SW     = ws + 21504;                // 64*1024 = 65536
    float* XW     = ws + 87040;                // 256*1024 = 262144
    float* T1     = ws + 349184;               // 256*1024 = 262144
    float* c0row  = ws + 611328;               // 2048
    float* TB     = ws + 742400;               // 256*2048 = 524288
    short* T1p    = (short*)(ws + 1266688);    // 256*1024 bf16 = 131,072 float slots
    short* A1p    = (short*)(ws + 1790976);    // 16384*1024 bf16 = 8,388,608 float slots
    short* Wx2a   = (short*)(ws + 10179584);   // 1024*512 bf16 = 262,144 float slots
    short* Wb1p   = (short*)(ws + 10441728);   // 512*2048 bf16 = 524,288 float slots
    short* W12p   = (short*)(ws + 10966016);   // 1024*2048 bf16 = 1,048,576 float slots
    int*   cnt    = (int*)(ws + 12014592);     // 4 ints: rnn-step, (unused), (unused), (unused)

    prep_kernel  <<<2177, 256, 0, stream>>>(stoich, Wx1, Wx2, Wb1, X, R, bx1, bx2, bb1, kpp, qpp,
                                            SW, Wx2a, Wb1p, XW, T1, wrow, hb0, dacc, out,
                                            c0row, cY, cnt);
    mid_kernel   <<<4312, 512, 0, stream>>>(XW, T1, SW, A1p, T1p, Y, Wih, Whh, bh, Wb1,
                                            kp, qp, hb0, hb1, cnt, cY, Wx2a, Wb1p, W12p);
    tbgemm_kernel<<<64,   256, 0, stream>>>(T1p, W12p, cY, c0row, Wb1, times_t, times_tau, kp, TB);
    gemm_big     <<<dim3(64, 8), 512, 0, stream>>>(A1p, W12p, TB, wrow, dacc);
    out_kernel   <<<8,    256, 0, stream>>>(dacc, Wb2, out);
}